// Round 1
// baseline (750.861 us; speedup 1.0000x reference)
//
#include <hip/hip_runtime.h>
#include <hip/hip_bf16.h>
#include <math.h>

// Problem constants
#define NW    32768   // B*W = 512*64 windows
#define G     4       // windows per block (was 8; halves LDS -> 8 blocks/CU, 100% occupancy)
#define NBLK  (NW / G)
#define NT    256

// Dims
#define ND    172     // NODE_DIM = EDGE_DIM = TIME_DIM
#define EVD   347     // EVENT_DIM
#define HID   64
#define D2    128
#define MLPD  76

// ---- Workspace: bf16 weights pre-packed in MFMA B-fragment order (unchanged) ----
// fragment = 64 lanes x 8 bf16; addr = (frag_id*64 + lane)*8; lane=(q<<4)|mr;
// element j of lane: B[n = nt*16+mr][k = ks*32+q*8+j] (0 if OOB).
#define W1OFF  0
#define G1OFF  (121 * 512)
#define G2OFF  (145 * 512)
#define ATTOFF (153 * 512)
#define NFRAG  217          // total ws = 217*512 bf16 = 222208 B

// ---- LDS byte layout (17280 B -> 8 blocks/CU @ 256 thr = 32 waves/CU), overlays ----
//  EF   bf16[12][360] @ 0      (8640)   phases 0-1 (garbage reads to row 15 ok)
//  U    bf16[24][200] @ 0      (9600)   2a out (rows 0-11 u0, 12-23 u1); overlays EF
//  EV   bf16[12][184] @ 9600   (4416)   phase-1 out, dead after 2a
//  H    bf16[24][72]  @ 9600   (3456)   2b out (overlays EV; garbage reads to row 31)
//  FEATB bf16[12][136]@ 0      (3264)   2c out (overlays U)
//  PQ   f32[12][128]  @ 3328   (6144)   2d out
//  SRCF f32[4][128]   @ 15232  (2048)   2c out (src feat, l==2 rows)
//  SC   f32[1408]     @ 9600   (5632)   phase-3 scratch (H dead)
#define B_EF    0
#define B_U     0
#define B_EV    9600
#define B_H     9600
#define B_FEATB 0
#define B_PQ    3328
#define B_SRCF  15232
#define B_SC    9600
#define LDS_BYTES 17280

#define EFS 360
#define EVS 184
#define US  200
#define HS  72
#define FBS 136

typedef __attribute__((ext_vector_type(8))) short bf16x8;
typedef __attribute__((ext_vector_type(4))) float f32x4;

static __device__ __forceinline__ short f2bf(float f) {
  union { __hip_bfloat16 h; short s; } u;
  u.h = __float2bfloat16(f);
  return u.s;
}
static __device__ __forceinline__ float bf2f(short s) {
  union { float f; unsigned u; } u;
  u.u = ((unsigned)(unsigned short)s) << 16;
  return u.f;
}

// ============ prep: pack all MFMA weights as bf16 fragments into ws ============
__global__ __launch_bounds__(256) void prep_weights(
    const float* __restrict__ w1, const float* __restrict__ g1,
    const float* __restrict__ g2, const float* __restrict__ a1,
    const float* __restrict__ a2, short* __restrict__ ws)
{
  const int t = blockIdx.x * 256 + threadIdx.x;
  if (t >= NFRAG * 64) return;
  const int fid  = t >> 6;
  const int lane = t & 63;
  const int q = lane >> 4, mr = lane & 15;
  bf16x8 o;
  if (fid < 121) {
    const int nt = fid / 11, ks = fid - 11 * nt;
    const int n = nt * 16 + mr, k0 = ks * 32 + q * 8;
#pragma unroll
    for (int j = 0; j < 8; ++j) {
      const int k = k0 + j;
      o[j] = (n < ND && k < EVD) ? f2bf(w1[n * EVD + k]) : (short)0;
    }
  } else if (fid < 145) {
    const int f = fid - 121, nt = f / 6, ks = f - 6 * nt;
    const int n = nt * 16 + mr, k0 = ks * 32 + q * 8;
#pragma unroll
    for (int j = 0; j < 8; ++j) {
      const int k = k0 + j;
      o[j] = (k < ND) ? f2bf(g1[n * ND + k]) : (short)0;
    }
  } else if (fid < 153) {
    const int f = fid - 145, nt = f / 2, ks = f - 2 * nt;
    const int n = nt * 16 + mr, k0 = ks * 32 + q * 8;
#pragma unroll
    for (int j = 0; j < 8; ++j) o[j] = f2bf(g2[n * HID + k0 + j]);
  } else {
    const int f = fid - 153, nt = f / 4, ks = f - 4 * nt;
    const int n = nt * 16 + mr, k0 = ks * 32 + q * 8;
    const float* src = (n < D2) ? (a1 + n * D2) : (a2 + (n - D2) * D2);
#pragma unroll
    for (int j = 0; j < 8; ++j) o[j] = f2bf(src[k0 + j]);
  }
  *(bf16x8*)&ws[(long)t * 8] = o;
}

__global__ __launch_bounds__(256, 8) void tempme_fused(
    const int*   __restrict__ node_idx,      // (NW, 6)
    const int*   __restrict__ edge_idx,      // (NW, 3)
    const int*   __restrict__ cat_feat,      // (NW, 1)
    const float* __restrict__ t_records,     // (NW, 3)
    const float* __restrict__ edge_identify, // (NW, 3, 3)
    const float* __restrict__ node_embed,    // (10000, 172)
    const float* __restrict__ edge_embed,    // (200000, 172)
    const float* __restrict__ basis_freq,    // (172,)
    const float* __restrict__ phase,         // (172,)
    const float* __restrict__ lin_event_b,   // (172,)
    const float* __restrict__ gcn_b1,        // (64,)
    const float* __restrict__ gcn_b2,        // (64,)
    const float* __restrict__ att_w1_b,      // (128,)
    const float* __restrict__ att_w2_b,      // (128,)
    const float* __restrict__ att_m1_w,      // (64, 128)
    const float* __restrict__ att_m1_b,      // (64,)
    const float* __restrict__ att_m2_w,      // (64, 64)
    const float* __restrict__ att_m2_b,      // (64,)
    const float* __restrict__ mlp_w1,        // (76, 76)
    const float* __restrict__ mlp_b1,        // (76,)
    const float* __restrict__ mlp_w2,        // (64, 76)
    const float* __restrict__ mlp_b2,        // (64,)
    const float* __restrict__ mlp_w3,        // (1, 64)
    const float* __restrict__ mlp_b3,        // (1,)
    const short* __restrict__ ws,            // packed bf16 weights
    float*       __restrict__ out)           // (NW,)
{
  __shared__ __align__(16) unsigned char smem[LDS_BYTES];
  short* EF    = (short*)&smem[B_EF];
  short* EV    = (short*)&smem[B_EV];
  short* U     = (short*)&smem[B_U];
  short* Hs    = (short*)&smem[B_H];
  short* FEATB = (short*)&smem[B_FEATB];
  float* SRCF  = (float*)&smem[B_SRCF];
  float* PQ    = (float*)&smem[B_PQ];
  float* SC    = (float*)&smem[B_SC];

  const int tid  = threadIdx.x;
  const int lane = tid & 63;
  const int wv   = tid >> 6;
  const int q    = lane >> 4;   // MFMA quad
  const int mr   = lane & 15;   // MFMA row/col-within-tile
  const int bw0  = blockIdx.x * G;

  // ============ phase 0: build ef bf16[12][360]; wave w owns rows w,w+4,w+8 ============
#pragma unroll 1
  for (int i = 0; i < 3; ++i) {
    const int r   = wv + 4 * i;
    const int g   = r / 3;
    const int l   = r - 3 * g;
    const int bw  = bw0 + g;
    const int rid = bw * 3 + l;
    const int e   = edge_idx[rid];
    const float dt = t_records[bw * 3 + 2] - t_records[rid];
    const float* erow = edge_embed + (long)e * ND;
#pragma unroll 2
    for (int c = 0; c < 6; ++c) {
      const int k = c * 64 + lane;   // 0..383
      if (k < 352) {                 // 347..351 = K-pad (zero)
        float v = 0.f;
        if (k < ND) v = erow[k];
        else if (k < ND + 3) v = edge_identify[rid * 3 + (k - ND)];
        else if (k < EVD) {
          const int d = k - (ND + 3);
          v = __cosf(fmaf(dt, basis_freq[d], phase[d]));
        }
        EF[r * EFS + k] = f2bf(v);
      }
    }
  }
  __syncthreads();

  // ============ phase 1 (MFMA): EV[12][172] = EF[12][347] @ lin_event_w^T ============
  // M=12 (1 m-tile, rows 12-15 garbage/discarded). Wave w owns n-tiles {w, w+4, w+8}.
  {
    const int nnt = (wv == 3) ? 2 : 3;
    f32x4 acc[3];
#pragma unroll
    for (int t = 0; t < 3; ++t) acc[t] = (f32x4){0.f, 0.f, 0.f, 0.f};

#pragma unroll 2
    for (int ks = 0; ks < 11; ++ks) {
      const int k0 = ks * 32 + q * 8;
      const bf16x8 a0 = *(const bf16x8*)&EF[mr * EFS + k0];
#pragma unroll 1
      for (int t = 0; t < nnt; ++t) {
        const int nt = wv + 4 * t;
        const bf16x8 b = *(const bf16x8*)&ws[W1OFF + ((nt * 11 + ks) * 64 + lane) * 8];
        acc[t] = __builtin_amdgcn_mfma_f32_16x16x32_bf16(a0, b, acc[t], 0, 0, 0);
      }
    }
#pragma unroll 1
    for (int t = 0; t < nnt; ++t) {
      const int n = (wv + 4 * t) * 16 + mr;
      const float bo = (n < ND) ? lin_event_b[n] : 0.f;
#pragma unroll
      for (int reg = 0; reg < 4; ++reg) {
        const int m = q * 4 + reg;
        if (m < 12) EV[m * EVS + n] = f2bf(acc[t][reg] + bo);
      }
    }
  }
  __syncthreads();

  // ============ phase 2a: U rows: u0=s+relu(t+e) (0..11), u1=t+relu(s+e) (12..23) ============
#pragma unroll 1
  for (int i = 0; i < 3; ++i) {
    const int r  = wv + 4 * i;
    const int g  = r / 3;
    const int l  = r - 3 * g;
    const int bw = bw0 + g;
    const int si = node_idx[bw * 6 + 2 * l];
    const int ti = node_idx[bw * 6 + 2 * l + 1];
#pragma unroll
    for (int c = 0; c < 3; ++c) {
      const int k = c * 64 + lane;  // 0..191
      float u0v = 0.f, u1v = 0.f;
      if (k < ND) {
        const float e = bf2f(EV[r * EVS + k]);
        const float s = node_embed[(long)si * ND + k];
        const float t = node_embed[(long)ti * ND + k];
        u0v = s + fmaxf(t + e, 0.f);
        u1v = t + fmaxf(s + e, 0.f);
      }
      U[r * US + k]        = f2bf(u0v);   // k in [172,192) zero = K-pad
      U[(12 + r) * US + k] = f2bf(u1v);
    }
  }
  __syncthreads();

  // ============ phase 2b (MFMA): H[24][64] = relu(U[24][192] @ gcn_w1^T + b1) ============
  // M=24 -> 2 m-tiles; wave: mtile=wv>>1, n-tiles {2*(wv&1), 2*(wv&1)+1}
  {
    const int mtile = wv >> 1;
    const int ntb   = (wv & 1) * 2;
    f32x4 acc[2];
#pragma unroll
    for (int tt = 0; tt < 2; ++tt) acc[tt] = (f32x4){0.f, 0.f, 0.f, 0.f};
#pragma unroll 2
    for (int ks = 0; ks < 6; ++ks) {
      const int k0 = ks * 32 + q * 8;
      const bf16x8 a = *(const bf16x8*)&U[(mtile * 16 + mr) * US + k0];
#pragma unroll 1
      for (int tt = 0; tt < 2; ++tt) {
        const int nt = ntb + tt;
        const bf16x8 b = *(const bf16x8*)&ws[G1OFF + ((nt * 6 + ks) * 64 + lane) * 8];
        acc[tt] = __builtin_amdgcn_mfma_f32_16x16x32_bf16(a, b, acc[tt], 0, 0, 0);
      }
    }
#pragma unroll 1
    for (int tt = 0; tt < 2; ++tt) {
      const int j = (ntb + tt) * 16 + mr;
      const float b1 = gcn_b1[j];
#pragma unroll
      for (int reg = 0; reg < 4; ++reg) {
        const int m = mtile * 16 + q * 4 + reg;
        if (m < 24) Hs[m * HS + j] = f2bf(fmaxf(acc[tt][reg] + b1, 0.f));
      }
    }
  }
  __syncthreads();

  // ============ phase 2c (MFMA): FEATB/SRCF = H @ gcn_w2^T + b2 ============
  {
    const int mtile = wv >> 1;
    const int ntb   = (wv & 1) * 2;
    f32x4 acc[2];
#pragma unroll
    for (int tt = 0; tt < 2; ++tt) acc[tt] = (f32x4){0.f, 0.f, 0.f, 0.f};
#pragma unroll
    for (int ks = 0; ks < 2; ++ks) {
      const int k0 = ks * 32 + q * 8;
      const bf16x8 a = *(const bf16x8*)&Hs[(mtile * 16 + mr) * HS + k0];
#pragma unroll 1
      for (int tt = 0; tt < 2; ++tt) {
        const int nt = ntb + tt;
        const bf16x8 b = *(const bf16x8*)&ws[G2OFF + ((nt * 2 + ks) * 64 + lane) * 8];
        acc[tt] = __builtin_amdgcn_mfma_f32_16x16x32_bf16(a, b, acc[tt], 0, 0, 0);
      }
    }
#pragma unroll 1
    for (int tt = 0; tt < 2; ++tt) {
      const int j = (ntb + tt) * 16 + mr;
      const float b2 = gcn_b2[j];
#pragma unroll
      for (int reg = 0; reg < 4; ++reg) {
        const int m = mtile * 16 + q * 4 + reg;
        if (m < 24) {
          const int d = (m < 12) ? 0 : 1;
          const int r = (m < 12) ? m : m - 12;
          const float v = acc[tt][reg] + b2;
          const int n = d * HID + j;
          FEATB[r * FBS + n] = f2bf(v);
          if (r % 3 == 2) SRCF[(r / 3) * 128 + n] = v;   // src feat, fp32
        }
      }
    }
  }
  __syncthreads();

  // ============ phase 2d (MFMA): PQ = feat @ [att_w1 | att_w2]^T + bias ============
  // M=12(+4 pad), N=256 (n<128: Wp, n>=128: Wq), K=128. Row r keeps Wp if l==2 else Wq.
  {
    f32x4 acc[4];
#pragma unroll
    for (int tt = 0; tt < 4; ++tt) acc[tt] = (f32x4){0.f, 0.f, 0.f, 0.f};
#pragma unroll 2
    for (int ks = 0; ks < 4; ++ks) {
      const int k0 = ks * 32 + q * 8;
      const bf16x8 a0 = *(const bf16x8*)&FEATB[mr * FBS + k0];
#pragma unroll 1
      for (int tt = 0; tt < 4; ++tt) {
        const int nt = wv * 4 + tt;
        const bf16x8 b = *(const bf16x8*)&ws[ATTOFF + ((nt * 4 + ks) * 64 + lane) * 8];
        acc[tt] = __builtin_amdgcn_mfma_f32_16x16x32_bf16(a0, b, acc[tt], 0, 0, 0);
      }
    }
#pragma unroll 1
    for (int tt = 0; tt < 4; ++tt) {
      const int n = (wv * 4 + tt) * 16 + mr;   // 0..255
      const float bias = (n < D2) ? att_w1_b[n] : att_w2_b[n - D2];
#pragma unroll
      for (int reg = 0; reg < 4; ++reg) {
        const int m = q * 4 + reg;
        if (m < 12) {
          const int l = m % 3;
          if (l == 2) { if (n < D2)  PQ[m * 128 + n]        = acc[tt][reg] + bias; }
          else        { if (n >= D2) PQ[m * 128 + (n - D2)] = acc[tt][reg] + bias; }
        }
      }
    }
  }
  __syncthreads();

  // ============ phase 3: softmax/out + MLP head (fp32 VALU; one window per wave) ============
  {
    float* sc_out = SC;           // 4*128
    float* sc_m1  = SC + 512;     // 4*64
    float* sc_x   = SC + 768;     // 4*80
    float* sc_h1  = SC + 1088;    // 4*80
    const int g  = wv;
    const int bw = bw0 + g;

    const float p0  = PQ[(3 * g + 2) * 128 + lane];
    const float p1  = PQ[(3 * g + 2) * 128 + 64 + lane];
    const float q00 = PQ[(3 * g + 0) * 128 + lane];
    const float q01 = PQ[(3 * g + 0) * 128 + 64 + lane];
    const float q10 = PQ[(3 * g + 1) * 128 + lane];
    const float q11 = PQ[(3 * g + 1) * 128 + 64 + lane];

    float s0 = p0 * q00 + p1 * q01;
    float s1 = p0 * q10 + p1 * q11;
#pragma unroll
    for (int off = 32; off >= 1; off >>= 1) {
      s0 += __shfl_xor(s0, off, 64);
      s1 += __shfl_xor(s1, off, 64);
    }
    const float mx = fmaxf(s0, s1);
    const float e0 = __expf(s0 - mx), e1 = __expf(s1 - mx);
    const float inv = 1.f / (e0 + e1);
    const float a0 = e0 * inv, a1 = e1 * inv;
    sc_out[g * 128 + lane]      = SRCF[g * 128 + lane]      + a0 * q00 + a1 * q10;
    sc_out[g * 128 + 64 + lane] = SRCF[g * 128 + 64 + lane] + a0 * q01 + a1 * q11;

    // m1 = relu(att_m1 @ out + b) — dual accumulator chains
    {
      float m1a = att_m1_b[lane], m1b = 0.f;
      const float* wr = att_m1_w + lane * D2;
      const float* ob = sc_out + g * 128;
#pragma unroll 2
      for (int d = 0; d < D2; d += 8) {
        const float4 wA = *(const float4*)(wr + d);
        const float4 oA = *(const float4*)&ob[d];
        const float4 wB = *(const float4*)(wr + d + 4);
        const float4 oB = *(const float4*)&ob[d + 4];
        m1a = fmaf(wA.x, oA.x, fmaf(wA.y, oA.y, fmaf(wA.z, oA.z, fmaf(wA.w, oA.w, m1a))));
        m1b = fmaf(wB.x, oB.x, fmaf(wB.y, oB.y, fmaf(wB.z, oB.z, fmaf(wB.w, oB.w, m1b))));
      }
      sc_m1[g * 64 + lane] = fmaxf(m1a + m1b, 0.f);
    }

    // h = att_m2 @ m1 + b
    float hv;
    {
      float ha = att_m2_b[lane], hb = 0.f;
      const float* wr = att_m2_w + lane * HID;
      const float* mb = sc_m1 + g * 64;
#pragma unroll 2
      for (int d = 0; d < HID; d += 8) {
        const float4 wA = *(const float4*)(wr + d);
        const float4 mA = *(const float4*)&mb[d];
        const float4 wB = *(const float4*)(wr + d + 4);
        const float4 mB = *(const float4*)&mb[d + 4];
        ha = fmaf(wA.x, mA.x, fmaf(wA.y, mA.y, fmaf(wA.z, mA.z, fmaf(wA.w, mA.w, ha))));
        hb = fmaf(wB.x, mB.x, fmaf(wB.y, mB.y, fmaf(wB.z, mB.z, fmaf(wB.w, mB.w, hb))));
      }
      hv = ha + hb;
    }
    // x = concat(h, one_hot(cat,12))
    sc_x[g * 80 + lane] = hv;
    if (lane < 12) {
      const int cat = cat_feat[bw];
      sc_x[g * 80 + 64 + lane] = (cat == lane) ? 1.f : 0.f;
    }

    // h1 = relu(mlp_w1 @ x + b1) : 76 outputs (76 = 9*8 + 4)
    const float* xb = sc_x + g * 80;
    {
      float h1a = mlp_b1[lane], h1b = 0.f;
      const float* wr = mlp_w1 + lane * MLPD;
#pragma unroll 3
      for (int k = 0; k < 72; k += 8) {
        const float4 wA = *(const float4*)(wr + k);
        const float4 xA = *(const float4*)&xb[k];
        const float4 wB = *(const float4*)(wr + k + 4);
        const float4 xB = *(const float4*)&xb[k + 4];
        h1a = fmaf(wA.x, xA.x, fmaf(wA.y, xA.y, fmaf(wA.z, xA.z, fmaf(wA.w, xA.w, h1a))));
        h1b = fmaf(wB.x, xB.x, fmaf(wB.y, xB.y, fmaf(wB.z, xB.z, fmaf(wB.w, xB.w, h1b))));
      }
      {
        const float4 wA = *(const float4*)(wr + 72);
        const float4 xA = *(const float4*)&xb[72];
        h1a = fmaf(wA.x, xA.x, fmaf(wA.y, xA.y, fmaf(wA.z, xA.z, fmaf(wA.w, xA.w, h1a))));
      }
      sc_h1[g * 80 + lane] = fmaxf(h1a + h1b, 0.f);
      if (lane < 12) {
        float hca = mlp_b1[64 + lane], hcb = 0.f;
        const float* wr2 = mlp_w1 + (64 + lane) * MLPD;
#pragma unroll 3
        for (int k = 0; k < 72; k += 8) {
          const float4 wA = *(const float4*)(wr2 + k);
          const float4 xA = *(const float4*)&xb[k];
          const float4 wB = *(const float4*)(wr2 + k + 4);
          const float4 xB = *(const float4*)&xb[k + 4];
          hca = fmaf(wA.x, xA.x, fmaf(wA.y, xA.y, fmaf(wA.z, xA.z, fmaf(wA.w, xA.w, hca))));
          hcb = fmaf(wB.x, xB.x, fmaf(wB.y, xB.y, fmaf(wB.z, xB.z, fmaf(wB.w, xB.w, hcb))));
        }
        {
          const float4 wA = *(const float4*)(wr2 + 72);
          const float4 xA = *(const float4*)&xb[72];
          hca = fmaf(wA.x, xA.x, fmaf(wA.y, xA.y, fmaf(wA.z, xA.z, fmaf(wA.w, xA.w, hca))));
        }
        sc_h1[g * 80 + 64 + lane] = fmaxf(hca + hcb, 0.f);
      }
    }

    // h2 = relu(mlp_w2 @ h1 + b2) ; z = mlp_w3 @ h2 + b3 ; sigmoid
    float h2;
    {
      float h2a = mlp_b2[lane], h2b = 0.f;
      const float* wr = mlp_w2 + lane * MLPD;
      const float* hb = sc_h1 + g * 80;
#pragma unroll 3
      for (int k = 0; k < 72; k += 8) {
        const float4 wA = *(const float4*)(wr + k);
        const float4 hA = *(const float4*)&hb[k];
        const float4 wB = *(const float4*)(wr + k + 4);
        const float4 hB = *(const float4*)&hb[k + 4];
        h2a = fmaf(wA.x, hA.x, fmaf(wA.y, hA.y, fmaf(wA.z, hA.z, fmaf(wA.w, hA.w, h2a))));
        h2b = fmaf(wB.x, hB.x, fmaf(wB.y, hB.y, fmaf(wB.z, hB.z, fmaf(wB.w, hB.w, h2b))));
      }
      {
        const float4 wA = *(const float4*)(wr + 72);
        const float4 hA = *(const float4*)&hb[72];
        h2a = fmaf(wA.x, hA.x, fmaf(wA.y, hA.y, fmaf(wA.z, hA.z, fmaf(wA.w, hA.w, h2a))));
      }
      h2 = h2a + h2b;
    }
    h2 = fmaxf(h2, 0.f);
    float zz = mlp_w3[lane] * h2;
#pragma unroll
    for (int off = 32; off >= 1; off >>= 1) zz += __shfl_xor(zz, off, 64);
    if (lane == 0) out[bw] = 1.f / (1.f + __expf(-(zz + mlp_b3[0])));
  }
}

extern "C" void kernel_launch(void* const* d_in, const int* in_sizes, int n_in,
                              void* d_out, int out_size, void* d_ws, size_t ws_size,
                              hipStream_t stream) {
  short* ws = (short*)d_ws;
  prep_weights<<<(NFRAG * 64 + 255) / 256, 256, 0, stream>>>(
      (const float*)d_in[10],  // lin_event_w
      (const float*)d_in[12],  // gcn_w1
      (const float*)d_in[14],  // gcn_w2
      (const float*)d_in[16],  // att_w1_w
      (const float*)d_in[18],  // att_w2_w
      ws);
  tempme_fused<<<NBLK, NT, 0, stream>>>(
      (const int*)d_in[0],    // node_idx
      (const int*)d_in[1],    // edge_idx
      (const int*)d_in[2],    // cat_feat
      (const float*)d_in[3],  // t_records
      (const float*)d_in[4],  // edge_identify
      // d_in[5] cut_time_l unused by reference
      (const float*)d_in[6],  // node_embed
      (const float*)d_in[7],  // edge_embed
      (const float*)d_in[8],  // basis_freq
      (const float*)d_in[9],  // phase
      (const float*)d_in[11],                          // lin_event_b
      (const float*)d_in[13],                          // gcn_b1
      (const float*)d_in[15],                          // gcn_b2
      (const float*)d_in[17],                          // att_w1_b
      (const float*)d_in[19],                          // att_w2_b
      (const float*)d_in[20], (const float*)d_in[21],  // att_m1
      (const float*)d_in[22], (const float*)d_in[23],  // att_m2
      (const float*)d_in[24], (const float*)d_in[25],  // mlp1
      (const float*)d_in[26], (const float*)d_in[27],  // mlp2
      (const float*)d_in[28], (const float*)d_in[29],  // mlp3
      ws,
      (float*)d_out);
}

// Round 3
// 553.538 us; speedup vs baseline: 1.3565x; 1.3565x over previous
//
#include <hip/hip_runtime.h>
#include <hip/hip_bf16.h>
#include <math.h>

// Problem constants
#define NW    32768   // B*W = 512*64 windows
#define G     8       // windows per block
#define NBLK  (NW / G)
#define NT    256

// Dims
#define ND    172     // NODE_DIM = EDGE_DIM = TIME_DIM
#define EVD   347     // EVENT_DIM
#define HID   64
#define D2    128
#define MLPD  76

// ---- Workspace layout ----
// [0, 222208) bytes : bf16 MFMA B-fragments (unchanged packing)
//   fragment = 64 lanes x 8 bf16; addr = (frag_id*64 + lane)*8; lane=(q<<4)|mr;
//   element j of lane: B[n = nt*16+mr][k = ks*32+q*8+j] (0 if OOB).
#define W1OFF  0
#define G1OFF  (121 * 512)
#define G2OFF  (145 * 512)
#define ATTOFF (153 * 512)
#define NFRAG  217          // bf16 region = 217*512 bf16 = 222208 B
// [222208, 317440) bytes : fp32 k-tiled transposed tables for phase-3 layers.
//   table[kb][n] = float4(w[n][4kb..4kb+3]); coalesced: lane n reads [kb][n].
#define WSF_BYTE_OFF 222208
#define M1OFF4 0            // att_m1 [32][64]  (K=128)
#define M2OFF4 2048         // att_m2 [16][64]  (K=64)
#define W1OFF4 3072         // mlp_w1 [20][80]  (K=76 pad 80, n pad 80, zeros)
#define W2OFF4 4672         // mlp_w2 [20][64]  (K=76 pad 80, zeros)
#define NF4    5952         // total float4 = 95232 B; ws total = 317440 B

// ---- LDS byte layout (34816 B -> 4 blocks/CU), liveness overlays ----
//  EF   bf16[32][360] @ 0      (23040)  phases 0-1 (rows 24+ garbage)
//  EV   bf16[24][184] @ 25600  (8832)   phase-1 out, dead after 2a
//  U    bf16[64][200] @ 0      (25600)  2a out (rows 0-23 u0, 32-55 u1)
//  H    bf16[64][72]  @ 25600  (9216)   2b out, dead after 2c
//  FEATB bf16[32][136]@ 0      (8704)   2c out (rows 0-23 valid)
//  SRCF f32[8][128]   @ 20992  (4096)   2c out (src feat, l==2 rows)
//  PQ   f32[24][128]  @ 8704   (12288)  2d out (live through phase 3!)
//  SC   f32[8][208]   @ 25600  (6656)   phase-3 scratch (H dead; NO PQ overlap)
#define B_EF    0
#define B_EV    25600
#define B_U     0
#define B_H     25600
#define B_FEATB 0
#define B_SRCF  20992
#define B_PQ    8704
#define B_SC    25600
#define LDS_BYTES 34816

#define EFS 360
#define EVS 184
#define US  200
#define HS  72
#define FBS 136

typedef __attribute__((ext_vector_type(8))) short bf16x8;
typedef __attribute__((ext_vector_type(4))) float f32x4;

// NOTE: inline function, NOT a macro — macro params collide with .x/.w member
// tokens in the preprocessor (Round-2 compile failure).
static __device__ __forceinline__ float dot4(float acc, const float4 a, const float4 b) {
  acc = fmaf(a.x, b.x, acc);
  acc = fmaf(a.y, b.y, acc);
  acc = fmaf(a.z, b.z, acc);
  acc = fmaf(a.w, b.w, acc);
  return acc;
}

static __device__ __forceinline__ short f2bf(float f) {
  union { __hip_bfloat16 h; short s; } u;
  u.h = __float2bfloat16(f);
  return u.s;
}
static __device__ __forceinline__ float bf2f(short s) {
  union { float f; unsigned u; } u;
  u.u = ((unsigned)(unsigned short)s) << 16;
  return u.f;
}

// ============ prep: pack all MFMA weights as bf16 fragments into ws ============
__global__ __launch_bounds__(256) void prep_weights(
    const float* __restrict__ w1, const float* __restrict__ g1,
    const float* __restrict__ g2, const float* __restrict__ a1,
    const float* __restrict__ a2, short* __restrict__ ws)
{
  const int t = blockIdx.x * 256 + threadIdx.x;
  if (t >= NFRAG * 64) return;
  const int fid  = t >> 6;
  const int lane = t & 63;
  const int q = lane >> 4, mr = lane & 15;
  bf16x8 o;
  if (fid < 121) {
    const int nt = fid / 11, ks = fid - 11 * nt;
    const int n = nt * 16 + mr, k0 = ks * 32 + q * 8;
#pragma unroll
    for (int j = 0; j < 8; ++j) {
      const int k = k0 + j;
      o[j] = (n < ND && k < EVD) ? f2bf(w1[n * EVD + k]) : (short)0;
    }
  } else if (fid < 145) {
    const int f = fid - 121, nt = f / 6, ks = f - 6 * nt;
    const int n = nt * 16 + mr, k0 = ks * 32 + q * 8;
#pragma unroll
    for (int j = 0; j < 8; ++j) {
      const int k = k0 + j;
      o[j] = (k < ND) ? f2bf(g1[n * ND + k]) : (short)0;
    }
  } else if (fid < 153) {
    const int f = fid - 145, nt = f / 2, ks = f - 2 * nt;
    const int n = nt * 16 + mr, k0 = ks * 32 + q * 8;
#pragma unroll
    for (int j = 0; j < 8; ++j) o[j] = f2bf(g2[n * HID + k0 + j]);
  } else {
    const int f = fid - 153, nt = f / 4, ks = f - 4 * nt;
    const int n = nt * 16 + mr, k0 = ks * 32 + q * 8;
    const float* src = (n < D2) ? (a1 + n * D2) : (a2 + (n - D2) * D2);
#pragma unroll
    for (int j = 0; j < 8; ++j) o[j] = f2bf(src[k0 + j]);
  }
  *(bf16x8*)&ws[(long)t * 8] = o;
}

// ============ prep: fp32 k-tiled transposed tables for phase-3 layers ============
__global__ __launch_bounds__(256) void prep_wf(
    const float* __restrict__ m1, const float* __restrict__ m2,
    const float* __restrict__ w1, const float* __restrict__ w2,
    float4* __restrict__ wf)
{
  const int t = blockIdx.x * 256 + threadIdx.x;
  if (t >= NF4) return;
  float4 o; o.x = 0.f; o.y = 0.f; o.z = 0.f; o.w = 0.f;
  if (t < M2OFF4) {                        // att_m1: [kb<32][n<64], K=128
    const int kb = t >> 6, n = t & 63;
    const float* s = m1 + n * D2 + kb * 4;
    o.x = s[0]; o.y = s[1]; o.z = s[2]; o.w = s[3];
  } else if (t < W1OFF4) {                 // att_m2: [kb<16][n<64], K=64
    const int u = t - M2OFF4, kb = u >> 6, n = u & 63;
    const float* s = m2 + n * HID + kb * 4;
    o.x = s[0]; o.y = s[1]; o.z = s[2]; o.w = s[3];
  } else if (t < W2OFF4) {                 // mlp_w1: [kb<20][n<80], pads zeroed
    const int u = t - W1OFF4, kb = u / 80, n = u - kb * 80;
    if (n < MLPD) {
#pragma unroll
      for (int j = 0; j < 4; ++j) {
        const int k = kb * 4 + j;
        ((float*)&o)[j] = (k < MLPD) ? w1[n * MLPD + k] : 0.f;
      }
    }
  } else {                                 // mlp_w2: [kb<20][n<64], k-pad zeroed
    const int u = t - W2OFF4, kb = u >> 6, n = u & 63;
#pragma unroll
    for (int j = 0; j < 4; ++j) {
      const int k = kb * 4 + j;
      ((float*)&o)[j] = (k < MLPD) ? w2[n * MLPD + k] : 0.f;
    }
  }
  wf[t] = o;
}

__global__ __launch_bounds__(256) void tempme_fused(
    const int*   __restrict__ node_idx,      // (NW, 6)
    const int*   __restrict__ edge_idx,      // (NW, 3)
    const int*   __restrict__ cat_feat,      // (NW, 1)
    const float* __restrict__ t_records,     // (NW, 3)
    const float* __restrict__ edge_identify, // (NW, 3, 3)
    const float* __restrict__ node_embed,    // (10000, 172)
    const float* __restrict__ edge_embed,    // (200000, 172)
    const float* __restrict__ basis_freq,    // (172,)
    const float* __restrict__ phase,         // (172,)
    const float* __restrict__ lin_event_b,   // (172,)
    const float* __restrict__ gcn_b1,        // (64,)
    const float* __restrict__ gcn_b2,        // (64,)
    const float* __restrict__ att_w1_b,      // (128,)
    const float* __restrict__ att_w2_b,      // (128,)
    const float* __restrict__ att_m1_b,      // (64,)
    const float* __restrict__ att_m2_b,      // (64,)
    const float* __restrict__ mlp_b1,        // (76,)
    const float* __restrict__ mlp_b2,        // (64,)
    const float* __restrict__ mlp_w3,        // (1, 64)
    const float* __restrict__ mlp_b3,        // (1,)
    const short* __restrict__ ws,            // packed bf16 weights
    const float4* __restrict__ wsf,          // packed fp32 phase-3 tables
    float*       __restrict__ out)           // (NW,)
{
  __shared__ __align__(16) unsigned char smem[LDS_BYTES];
  short* EF    = (short*)&smem[B_EF];
  short* EV    = (short*)&smem[B_EV];
  short* U     = (short*)&smem[B_U];
  short* Hs    = (short*)&smem[B_H];
  short* FEATB = (short*)&smem[B_FEATB];
  float* SRCF  = (float*)&smem[B_SRCF];
  float* PQ    = (float*)&smem[B_PQ];
  float* SC    = (float*)&smem[B_SC];

  const int tid  = threadIdx.x;
  const int lane = tid & 63;
  const int wv   = tid >> 6;
  const int q    = lane >> 4;   // MFMA quad
  const int mr   = lane & 15;   // MFMA row/col-within-tile
  const int bw0  = blockIdx.x * G;

  // ============ phase 0: build ef bf16[24][360]; wave w owns rows w,w+4,.. ============
#pragma unroll 1
  for (int i = 0; i < 6; ++i) {
    const int r   = wv + 4 * i;
    const int g   = r / 3;
    const int l   = r - 3 * g;
    const int bw  = bw0 + g;
    const int rid = bw * 3 + l;
    const int e   = edge_idx[rid];
    const float dt = t_records[bw * 3 + 2] - t_records[rid];
    const float* erow = edge_embed + (long)e * ND;
#pragma unroll 2
    for (int c = 0; c < 6; ++c) {
      const int k = c * 64 + lane;   // 0..383
      if (k < 352) {                 // 347..351 = K-pad (zero)
        float v = 0.f;
        if (k < ND) v = erow[k];
        else if (k < ND + 3) v = edge_identify[rid * 3 + (k - ND)];
        else if (k < EVD) {
          const int d = k - (ND + 3);
          v = __cosf(fmaf(dt, basis_freq[d], phase[d]));
        }
        EF[r * EFS + k] = f2bf(v);
      }
    }
  }
  __syncthreads();

  // ============ phase 1 (MFMA): EV[24][172] = EF[24][347] @ lin_event_w^T ============
  {
    const int nnt = (wv == 3) ? 2 : 3;   // wave w owns n-tiles {w, w+4, w+8}
    f32x4 acc[3][2];
#pragma unroll
    for (int t = 0; t < 3; ++t)
#pragma unroll
      for (int mt = 0; mt < 2; ++mt) acc[t][mt] = (f32x4){0.f, 0.f, 0.f, 0.f};

#pragma unroll 2
    for (int ks = 0; ks < 11; ++ks) {
      const int k0 = ks * 32 + q * 8;
      const bf16x8 a0 = *(const bf16x8*)&EF[mr * EFS + k0];
      const bf16x8 a1 = *(const bf16x8*)&EF[(16 + mr) * EFS + k0];
#pragma unroll 1
      for (int t = 0; t < nnt; ++t) {
        const int nt = wv + 4 * t;
        const bf16x8 b = *(const bf16x8*)&ws[W1OFF + ((nt * 11 + ks) * 64 + lane) * 8];
        acc[t][0] = __builtin_amdgcn_mfma_f32_16x16x32_bf16(a0, b, acc[t][0], 0, 0, 0);
        acc[t][1] = __builtin_amdgcn_mfma_f32_16x16x32_bf16(a1, b, acc[t][1], 0, 0, 0);
      }
    }
#pragma unroll 1
    for (int t = 0; t < nnt; ++t) {
      const int n = (wv + 4 * t) * 16 + mr;
      const float bo = (n < ND) ? lin_event_b[n] : 0.f;
#pragma unroll
      for (int mt = 0; mt < 2; ++mt)
#pragma unroll
        for (int reg = 0; reg < 4; ++reg) {
          const int m = mt * 16 + q * 4 + reg;
          if (m < 24) EV[m * EVS + n] = f2bf(acc[t][mt][reg] + bo);
        }
    }
  }
  __syncthreads();

  // ============ phase 2a: U rows: u0=s+relu(t+e) (0..23), u1=t+relu(s+e) (32..55) ============
#pragma unroll 1
  for (int i = 0; i < 6; ++i) {
    const int r  = wv + 4 * i;
    const int g  = r / 3;
    const int l  = r - 3 * g;
    const int bw = bw0 + g;
    const int si = node_idx[bw * 6 + 2 * l];
    const int ti = node_idx[bw * 6 + 2 * l + 1];
#pragma unroll
    for (int c = 0; c < 3; ++c) {
      const int k = c * 64 + lane;  // 0..191
      float u0v = 0.f, u1v = 0.f;
      if (k < ND) {
        const float e = bf2f(EV[r * EVS + k]);
        const float s = node_embed[(long)si * ND + k];
        const float t = node_embed[(long)ti * ND + k];
        u0v = s + fmaxf(t + e, 0.f);
        u1v = t + fmaxf(s + e, 0.f);
      }
      U[r * US + k]        = f2bf(u0v);   // k in [172,192) zero = K-pad
      U[(32 + r) * US + k] = f2bf(u1v);
    }
  }
  __syncthreads();

  // ============ phase 2b (MFMA): H[64][64] = relu(U[64][192] @ gcn_w1^T + b1) ============
  {
    f32x4 acc[4];
#pragma unroll
    for (int nt = 0; nt < 4; ++nt) acc[nt] = (f32x4){0.f, 0.f, 0.f, 0.f};
#pragma unroll 2
    for (int ks = 0; ks < 6; ++ks) {
      const int k0 = ks * 32 + q * 8;
      const bf16x8 a = *(const bf16x8*)&U[(wv * 16 + mr) * US + k0];
#pragma unroll 1
      for (int nt = 0; nt < 4; ++nt) {
        const bf16x8 b = *(const bf16x8*)&ws[G1OFF + ((nt * 6 + ks) * 64 + lane) * 8];
        acc[nt] = __builtin_amdgcn_mfma_f32_16x16x32_bf16(a, b, acc[nt], 0, 0, 0);
      }
    }
#pragma unroll 1
    for (int nt = 0; nt < 4; ++nt) {
      const int j = nt * 16 + mr;
      const float b1 = gcn_b1[j];
#pragma unroll
      for (int reg = 0; reg < 4; ++reg) {
        const int m = wv * 16 + q * 4 + reg;
        Hs[m * HS + j] = f2bf(fmaxf(acc[nt][reg] + b1, 0.f));
      }
    }
  }
  __syncthreads();

  // ============ phase 2c (MFMA): FEATB/SRCF = H @ gcn_w2^T + b2 ============
  {
    f32x4 acc[4];
#pragma unroll
    for (int nt = 0; nt < 4; ++nt) acc[nt] = (f32x4){0.f, 0.f, 0.f, 0.f};
#pragma unroll
    for (int ks = 0; ks < 2; ++ks) {
      const int k0 = ks * 32 + q * 8;
      const bf16x8 a = *(const bf16x8*)&Hs[(wv * 16 + mr) * HS + k0];
#pragma unroll 1
      for (int nt = 0; nt < 4; ++nt) {
        const bf16x8 b = *(const bf16x8*)&ws[G2OFF + ((nt * 2 + ks) * 64 + lane) * 8];
        acc[nt] = __builtin_amdgcn_mfma_f32_16x16x32_bf16(a, b, acc[nt], 0, 0, 0);
      }
    }
#pragma unroll 1
    for (int nt = 0; nt < 4; ++nt) {
      const int j = nt * 16 + mr;
      const float b2 = gcn_b2[j];
#pragma unroll
      for (int reg = 0; reg < 4; ++reg) {
        const int m = wv * 16 + q * 4 + reg;
        int d = -1, r = 0;
        if (m < 24) { d = 0; r = m; }
        else if (m >= 32 && m < 56) { d = 1; r = m - 32; }
        if (d >= 0) {
          const float v = acc[nt][reg] + b2;
          const int n = d * HID + j;
          FEATB[r * FBS + n] = f2bf(v);
          if (r % 3 == 2) SRCF[(r / 3) * 128 + n] = v;   // src feat, fp32
        }
      }
    }
  }
  __syncthreads();

  // ============ phase 2d (MFMA): PQ = feat @ [att_w1 | att_w2]^T + bias ============
  {
    f32x4 acc[4][2];
#pragma unroll
    for (int tt = 0; tt < 4; ++tt)
#pragma unroll
      for (int mt = 0; mt < 2; ++mt) acc[tt][mt] = (f32x4){0.f, 0.f, 0.f, 0.f};
#pragma unroll 2
    for (int ks = 0; ks < 4; ++ks) {
      const int k0 = ks * 32 + q * 8;
      const bf16x8 a0 = *(const bf16x8*)&FEATB[mr * FBS + k0];
      const bf16x8 a1 = *(const bf16x8*)&FEATB[(16 + mr) * FBS + k0];
#pragma unroll 1
      for (int tt = 0; tt < 4; ++tt) {
        const int nt = wv * 4 + tt;
        const bf16x8 b = *(const bf16x8*)&ws[ATTOFF + ((nt * 4 + ks) * 64 + lane) * 8];
        acc[tt][0] = __builtin_amdgcn_mfma_f32_16x16x32_bf16(a0, b, acc[tt][0], 0, 0, 0);
        acc[tt][1] = __builtin_amdgcn_mfma_f32_16x16x32_bf16(a1, b, acc[tt][1], 0, 0, 0);
      }
    }
#pragma unroll 1
    for (int tt = 0; tt < 4; ++tt) {
      const int n = (wv * 4 + tt) * 16 + mr;   // 0..255
      const float bias = (n < D2) ? att_w1_b[n] : att_w2_b[n - D2];
#pragma unroll
      for (int mt = 0; mt < 2; ++mt)
#pragma unroll
        for (int reg = 0; reg < 4; ++reg) {
          const int m = mt * 16 + q * 4 + reg;
          if (m < 24) {
            const int l = m % 3;
            if (l == 2) { if (n < D2)  PQ[m * 128 + n]        = acc[tt][mt][reg] + bias; }
            else        { if (n >= D2) PQ[m * 128 + (n - D2)] = acc[tt][mt][reg] + bias; }
          }
        }
    }
  }
  __syncthreads();

  // ============ phase 3: softmax/out + MLP head ============
  // Wave wv owns windows ga=2wv, gb=2wv+1; both windows share one weight stream
  // (coalesced float4 loads from wsf k-tiled transposed tables).
  {
    const int ga = wv * 2, gb = ga + 1;
    float* A_a = SC + ga * 208;  float* Bb_a = A_a + 128;   // per-window scratch
    float* A_b = SC + gb * 208;  float* Bb_b = A_b + 128;

    // softmax + out (written to A slots as fp32[128])
#pragma unroll 1
    for (int it = 0; it < 2; ++it) {
      const int g = ga + it;
      float* Ao = SC + g * 208;
      const float p0  = PQ[(3 * g + 2) * 128 + lane];
      const float p1  = PQ[(3 * g + 2) * 128 + 64 + lane];
      const float q00 = PQ[(3 * g + 0) * 128 + lane];
      const float q01 = PQ[(3 * g + 0) * 128 + 64 + lane];
      const float q10 = PQ[(3 * g + 1) * 128 + lane];
      const float q11 = PQ[(3 * g + 1) * 128 + 64 + lane];
      float s0 = p0 * q00 + p1 * q01;
      float s1 = p0 * q10 + p1 * q11;
#pragma unroll
      for (int off = 32; off >= 1; off >>= 1) {
        s0 += __shfl_xor(s0, off, 64);
        s1 += __shfl_xor(s1, off, 64);
      }
      const float mx = fmaxf(s0, s1);
      const float e0 = __expf(s0 - mx), e1 = __expf(s1 - mx);
      const float inv = 1.f / (e0 + e1);
      const float a0 = e0 * inv, a1 = e1 * inv;
      Ao[lane]      = SRCF[g * 128 + lane]      + a0 * q00 + a1 * q10;
      Ao[64 + lane] = SRCF[g * 128 + 64 + lane] + a0 * q01 + a1 * q11;
    }

    const float4* M1P = wsf + M1OFF4;
    const float4* M2P = wsf + M2OFF4;
    const float4* W1P = wsf + W1OFF4;
    const float4* W2P = wsf + W2OFF4;

    // m1 = relu(att_m1 @ out + b): K=128, out n=lane; both windows fused
    {
      float aa0 = 0.f, aa1 = 0.f, bb0 = 0.f, bb1 = 0.f;
#pragma unroll 4
      for (int kb = 0; kb < 32; kb += 2) {
        const float4 w0 = M1P[kb * 64 + lane];
        const float4 w1 = M1P[(kb + 1) * 64 + lane];
        const float4 xa0 = *(const float4*)&A_a[kb * 4];
        const float4 xa1 = *(const float4*)&A_a[kb * 4 + 4];
        const float4 xb0 = *(const float4*)&A_b[kb * 4];
        const float4 xb1 = *(const float4*)&A_b[kb * 4 + 4];
        aa0 = dot4(aa0, w0, xa0); aa1 = dot4(aa1, w1, xa1);
        bb0 = dot4(bb0, w0, xb0); bb1 = dot4(bb1, w1, xb1);
      }
      const float bi = att_m1_b[lane];
      Bb_a[lane] = fmaxf(bi + aa0 + aa1, 0.f);
      Bb_b[lane] = fmaxf(bi + bb0 + bb1, 0.f);
    }

    // h = att_m2 @ m1 + b: K=64
    float hv_a, hv_b;
    {
      float aa0 = 0.f, aa1 = 0.f, bb0 = 0.f, bb1 = 0.f;
#pragma unroll 4
      for (int kb = 0; kb < 16; kb += 2) {
        const float4 w0 = M2P[kb * 64 + lane];
        const float4 w1 = M2P[(kb + 1) * 64 + lane];
        const float4 xa0 = *(const float4*)&Bb_a[kb * 4];
        const float4 xa1 = *(const float4*)&Bb_a[kb * 4 + 4];
        const float4 xb0 = *(const float4*)&Bb_b[kb * 4];
        const float4 xb1 = *(const float4*)&Bb_b[kb * 4 + 4];
        aa0 = dot4(aa0, w0, xa0); aa1 = dot4(aa1, w1, xa1);
        bb0 = dot4(bb0, w0, xb0); bb1 = dot4(bb1, w1, xb1);
      }
      const float bi = att_m2_b[lane];
      hv_a = bi + aa0 + aa1;
      hv_b = bi + bb0 + bb1;
    }

    // x = concat(h, one_hot(cat,12), 0-pad to 80) -> A slots (out is dead)
    A_a[lane] = hv_a;
    A_b[lane] = hv_b;
    if (lane < 16) {
      const int ca = cat_feat[bw0 + ga];
      const int cb = cat_feat[bw0 + gb];
      A_a[64 + lane] = (lane < 12 && ca == lane) ? 1.f : 0.f;
      A_b[64 + lane] = (lane < 12 && cb == lane) ? 1.f : 0.f;
    }

    // h1 = relu(mlp_w1 @ x + b1): 76 outs (n=lane, n2=64+(lane&15)), K=80
    {
      float an = 0.f, an2 = 0.f, bn = 0.f, bn2 = 0.f;
      const int l2 = 64 + (lane & 15);
#pragma unroll 4
      for (int kb = 0; kb < 20; ++kb) {
        const float4 wn  = W1P[kb * 80 + lane];
        const float4 wn2 = W1P[kb * 80 + l2];
        const float4 xa = *(const float4*)&A_a[kb * 4];
        const float4 xb = *(const float4*)&A_b[kb * 4];
        an  = dot4(an,  wn,  xa); an2 = dot4(an2, wn2, xa);
        bn  = dot4(bn,  wn,  xb); bn2 = dot4(bn2, wn2, xb);
      }
      const float b1n = mlp_b1[lane];
      Bb_a[lane] = fmaxf(b1n + an, 0.f);
      Bb_b[lane] = fmaxf(b1n + bn, 0.f);
      if (lane < 16) {
        const float b1n2 = (lane < 12) ? mlp_b1[64 + lane] : 0.f;
        Bb_a[64 + lane] = fmaxf(b1n2 + an2, 0.f);   // rows 76..79 -> 0
        Bb_b[64 + lane] = fmaxf(b1n2 + bn2, 0.f);
      }
    }

    // h2 = relu(mlp_w2 @ h1 + b2); z = mlp_w3 @ h2 + b3; sigmoid
    {
      float ha = 0.f, hb = 0.f;
#pragma unroll 4
      for (int kb = 0; kb < 20; ++kb) {
        const float4 w  = W2P[kb * 64 + lane];
        const float4 xa = *(const float4*)&Bb_a[kb * 4];
        const float4 xb = *(const float4*)&Bb_b[kb * 4];
        ha = dot4(ha, w, xa);
        hb = dot4(hb, w, xb);
      }
      const float b2 = mlp_b2[lane];
      const float h2a = fmaxf(b2 + ha, 0.f);
      const float h2b = fmaxf(b2 + hb, 0.f);
      const float w3 = mlp_w3[lane];
      float za = w3 * h2a, zb = w3 * h2b;
#pragma unroll
      for (int off = 32; off >= 1; off >>= 1) {
        za += __shfl_xor(za, off, 64);
        zb += __shfl_xor(zb, off, 64);
      }
      if (lane == 0) {
        const float b3 = mlp_b3[0];
        out[bw0 + ga] = 1.f / (1.f + __expf(-(za + b3)));
        out[bw0 + gb] = 1.f / (1.f + __expf(-(zb + b3)));
      }
    }
  }
}

extern "C" void kernel_launch(void* const* d_in, const int* in_sizes, int n_in,
                              void* d_out, int out_size, void* d_ws, size_t ws_size,
                              hipStream_t stream) {
  short* ws = (short*)d_ws;
  float4* wsf = (float4*)((char*)d_ws + WSF_BYTE_OFF);
  prep_weights<<<(NFRAG * 64 + 255) / 256, 256, 0, stream>>>(
      (const float*)d_in[10],  // lin_event_w
      (const float*)d_in[12],  // gcn_w1
      (const float*)d_in[14],  // gcn_w2
      (const float*)d_in[16],  // att_w1_w
      (const float*)d_in[18],  // att_w2_w
      ws);
  prep_wf<<<(NF4 + 255) / 256, 256, 0, stream>>>(
      (const float*)d_in[20],  // att_m1_w
      (const float*)d_in[22],  // att_m2_w
      (const float*)d_in[24],  // mlp_w1
      (const float*)d_in[26],  // mlp_w2
      wsf);
  tempme_fused<<<NBLK, NT, 0, stream>>>(
      (const int*)d_in[0],    // node_idx
      (const int*)d_in[1],    // edge_idx
      (const int*)d_in[2],    // cat_feat
      (const float*)d_in[3],  // t_records
      (const float*)d_in[4],  // edge_identify
      // d_in[5] cut_time_l unused by reference
      (const float*)d_in[6],  // node_embed
      (const float*)d_in[7],  // edge_embed
      (const float*)d_in[8],  // basis_freq
      (const float*)d_in[9],  // phase
      (const float*)d_in[11],  // lin_event_b
      (const float*)d_in[13],  // gcn_b1
      (const float*)d_in[15],  // gcn_b2
      (const float*)d_in[17],  // att_w1_b
      (const float*)d_in[19],  // att_w2_b
      (const float*)d_in[21],  // att_m1_b
      (const float*)d_in[23],  // att_m2_b
      (const float*)d_in[25],  // mlp_b1
      (const float*)d_in[27],  // mlp_b2
      (const float*)d_in[28],  // mlp_w3
      (const float*)d_in[29],  // mlp_b3
      ws, wsf,
      (float*)d_out);
}

// Round 4
// 479.897 us; speedup vs baseline: 1.5646x; 1.1535x over previous
//
#include <hip/hip_runtime.h>
#include <hip/hip_bf16.h>
#include <math.h>

// Problem constants
#define NW    32768   // B*W = 512*64 windows
#define G     8       // windows per block
#define NBLK  (NW / G)
#define NT    256

// Dims
#define ND    172     // NODE_DIM = EDGE_DIM = TIME_DIM
#define EVD   347     // EVENT_DIM
#define HID   64
#define D2    128
#define MLPD  76

// ---- Workspace layout ----
// [0, 222208) bytes : bf16 MFMA B-fragments
//   fragment = 64 lanes x 8 bf16; addr = (frag_id*64 + lane)*8; lane=(q<<4)|mr;
//   element j of lane: B[n = nt*16+mr][k = ks*32+q*8+j] (0 if OOB).
#define W1OFF  0
#define G1OFF  (121 * 512)
#define G2OFF  (145 * 512)
#define ATTOFF (153 * 512)
#define NFRAG  217          // bf16 region = 217*512 bf16 = 222208 B
// [222208, 317440) bytes : fp32 k-tiled transposed tables for phase-3 layers.
//   table[kb][n] = float4(w[n][4kb..4kb+3]); coalesced: lane n reads [kb][n].
#define WSF_BYTE_OFF 222208
#define M1OFF4 0            // att_m1 [32][64]  (K=128)
#define M2OFF4 2048         // att_m2 [16][64]  (K=64)
#define W1OFF4 3072         // mlp_w1 [20][80]  (K=76 pad 80, n pad 80, zeros)
#define W2OFF4 4672         // mlp_w2 [20][64]  (K=76 pad 80, zeros)
#define NF4    5952         // total float4 = 95232 B; ws total = 317440 B

// ---- LDS byte layout (34816 B -> 4 blocks/CU), liveness overlays ----
//  EF   bf16[32][360] @ 0      (23040)  phases 0-1 (rows 24+ garbage)
//  EV   bf16[24][184] @ 25600  (8832)   phase-1 out, dead after 2a
//  U    bf16[64][200] @ 0      (25600)  2a out (rows 0-23 u0, 32-55 u1)
//  H    bf16[64][72]  @ 25600  (9216)   2b out, dead after 2c
//  FEATB bf16[32][136]@ 0      (8704)   2c out (rows 0-23 valid)
//  SRCF f32[8][128]   @ 20992  (4096)   2c out (src feat, l==2 rows)
//  PQ   f32[24][128]  @ 8704   (12288)  2d out (live through phase 3!)
//  SC   f32[8][208]   @ 25600  (6656)   phase-3 scratch (H dead; NO PQ overlap)
#define B_EF    0
#define B_EV    25600
#define B_U     0
#define B_H     25600
#define B_FEATB 0
#define B_SRCF  20992
#define B_PQ    8704
#define B_SC    25600
#define LDS_BYTES 34816

#define EFS 360
#define EVS 184
#define US  200
#define HS  72
#define FBS 136

typedef __attribute__((ext_vector_type(8))) short bf16x8;
typedef __attribute__((ext_vector_type(4))) float f32x4;

// inline function, NOT a macro — macro params collide with .x/.w member tokens
static __device__ __forceinline__ float dot4(float acc, const float4 a, const float4 b) {
  acc = fmaf(a.x, b.x, acc);
  acc = fmaf(a.y, b.y, acc);
  acc = fmaf(a.z, b.z, acc);
  acc = fmaf(a.w, b.w, acc);
  return acc;
}

static __device__ __forceinline__ short f2bf(float f) {
  union { __hip_bfloat16 h; short s; } u;
  u.h = __float2bfloat16(f);
  return u.s;
}
static __device__ __forceinline__ float bf2f(short s) {
  union { float f; unsigned u; } u;
  u.u = ((unsigned)(unsigned short)s) << 16;
  return u.f;
}

// ============ prep: pack all MFMA weights as bf16 fragments into ws ============
__global__ __launch_bounds__(256) void prep_weights(
    const float* __restrict__ w1, const float* __restrict__ g1,
    const float* __restrict__ g2, const float* __restrict__ a1,
    const float* __restrict__ a2, short* __restrict__ ws)
{
  const int t = blockIdx.x * 256 + threadIdx.x;
  if (t >= NFRAG * 64) return;
  const int fid  = t >> 6;
  const int lane = t & 63;
  const int q = lane >> 4, mr = lane & 15;
  bf16x8 o;
  if (fid < 121) {
    const int nt = fid / 11, ks = fid - 11 * nt;
    const int n = nt * 16 + mr, k0 = ks * 32 + q * 8;
#pragma unroll
    for (int j = 0; j < 8; ++j) {
      const int k = k0 + j;
      o[j] = (n < ND && k < EVD) ? f2bf(w1[n * EVD + k]) : (short)0;
    }
  } else if (fid < 145) {
    const int f = fid - 121, nt = f / 6, ks = f - 6 * nt;
    const int n = nt * 16 + mr, k0 = ks * 32 + q * 8;
#pragma unroll
    for (int j = 0; j < 8; ++j) {
      const int k = k0 + j;
      o[j] = (k < ND) ? f2bf(g1[n * ND + k]) : (short)0;
    }
  } else if (fid < 153) {
    const int f = fid - 145, nt = f / 2, ks = f - 2 * nt;
    const int n = nt * 16 + mr, k0 = ks * 32 + q * 8;
#pragma unroll
    for (int j = 0; j < 8; ++j) o[j] = f2bf(g2[n * HID + k0 + j]);
  } else {
    const int f = fid - 153, nt = f / 4, ks = f - 4 * nt;
    const int n = nt * 16 + mr, k0 = ks * 32 + q * 8;
    const float* src = (n < D2) ? (a1 + n * D2) : (a2 + (n - D2) * D2);
#pragma unroll
    for (int j = 0; j < 8; ++j) o[j] = f2bf(src[k0 + j]);
  }
  *(bf16x8*)&ws[(long)t * 8] = o;
}

// ============ prep: fp32 k-tiled transposed tables for phase-3 layers ============
__global__ __launch_bounds__(256) void prep_wf(
    const float* __restrict__ m1, const float* __restrict__ m2,
    const float* __restrict__ w1, const float* __restrict__ w2,
    float4* __restrict__ wf)
{
  const int t = blockIdx.x * 256 + threadIdx.x;
  if (t >= NF4) return;
  float4 o; o.x = 0.f; o.y = 0.f; o.z = 0.f; o.w = 0.f;
  if (t < M2OFF4) {                        // att_m1: [kb<32][n<64], K=128
    const int kb = t >> 6, n = t & 63;
    const float* s = m1 + n * D2 + kb * 4;
    o.x = s[0]; o.y = s[1]; o.z = s[2]; o.w = s[3];
  } else if (t < W1OFF4) {                 // att_m2: [kb<16][n<64], K=64
    const int u = t - M2OFF4, kb = u >> 6, n = u & 63;
    const float* s = m2 + n * HID + kb * 4;
    o.x = s[0]; o.y = s[1]; o.z = s[2]; o.w = s[3];
  } else if (t < W2OFF4) {                 // mlp_w1: [kb<20][n<80], pads zeroed
    const int u = t - W1OFF4, kb = u / 80, n = u - kb * 80;
    if (n < MLPD) {
#pragma unroll
      for (int j = 0; j < 4; ++j) {
        const int k = kb * 4 + j;
        ((float*)&o)[j] = (k < MLPD) ? w1[n * MLPD + k] : 0.f;
      }
    }
  } else {                                 // mlp_w2: [kb<20][n<64], k-pad zeroed
    const int u = t - W2OFF4, kb = u >> 6, n = u & 63;
#pragma unroll
    for (int j = 0; j < 4; ++j) {
      const int k = kb * 4 + j;
      ((float*)&o)[j] = (k < MLPD) ? w2[n * MLPD + k] : 0.f;
    }
  }
  wf[t] = o;
}

__global__ __launch_bounds__(256) void tempme_fused(
    const int*   __restrict__ node_idx,      // (NW, 6)
    const int*   __restrict__ edge_idx,      // (NW, 3)
    const int*   __restrict__ cat_feat,      // (NW, 1)
    const float* __restrict__ t_records,     // (NW, 3)
    const float* __restrict__ edge_identify, // (NW, 3, 3)
    const float* __restrict__ node_embed,    // (10000, 172)
    const float* __restrict__ edge_embed,    // (200000, 172)
    const float* __restrict__ basis_freq,    // (172,)
    const float* __restrict__ phase,         // (172,)
    const float* __restrict__ lin_event_b,   // (172,)
    const float* __restrict__ gcn_b1,        // (64,)
    const float* __restrict__ gcn_b2,        // (64,)
    const float* __restrict__ att_w1_b,      // (128,)
    const float* __restrict__ att_w2_b,      // (128,)
    const float* __restrict__ att_m1_b,      // (64,)
    const float* __restrict__ att_m2_b,      // (64,)
    const float* __restrict__ mlp_b1,        // (76,)
    const float* __restrict__ mlp_b2,        // (64,)
    const float* __restrict__ mlp_w3,        // (1, 64)
    const float* __restrict__ mlp_b3,        // (1,)
    const short* __restrict__ ws,            // packed bf16 weights
    const float4* __restrict__ wsf,          // packed fp32 phase-3 tables
    float*       __restrict__ out)           // (NW,)
{
  __shared__ __align__(16) unsigned char smem[LDS_BYTES];
  short* EF    = (short*)&smem[B_EF];
  short* EV    = (short*)&smem[B_EV];
  short* U     = (short*)&smem[B_U];
  short* Hs    = (short*)&smem[B_H];
  short* FEATB = (short*)&smem[B_FEATB];
  float* SRCF  = (float*)&smem[B_SRCF];
  float* PQ    = (float*)&smem[B_PQ];
  float* SC    = (float*)&smem[B_SC];

  const int tid  = threadIdx.x;
  const int lane = tid & 63;
  const int wv   = tid >> 6;
  const int q    = lane >> 4;   // MFMA quad
  const int mr   = lane & 15;   // MFMA row/col-within-tile
  const int bw0  = blockIdx.x * G;

  // ============ prefetch A: indices (wave-uniform scalar loads) ============
  int   eidx_[6], si_[6], ti_[6], rid_[6];
  float dt_[6];
#pragma unroll
  for (int i = 0; i < 6; ++i) {
    const int r = wv + 4 * i;
    const int g = r / 3;
    const int l = r - 3 * g;
    const int bw = bw0 + g;
    const int rid = bw * 3 + l;
    rid_[i]  = rid;
    eidx_[i] = edge_idx[rid];
    si_[i]   = node_idx[bw * 6 + 2 * l];
    ti_[i]   = node_idx[bw * 6 + 2 * l + 1];
    dt_[i]   = t_records[bw * 3 + 2] - t_records[rid];
  }

  // ============ prefetch B: edge-row gathers (18 loads all in flight) ============
  // pg[i][c]: k = c*64+lane; edge_embed row for k<172, edge_identify for 172..174.
  float pg[6][3];
#pragma unroll
  for (int i = 0; i < 6; ++i) {
    const float* erow = edge_embed + (long)eidx_[i] * ND;
#pragma unroll
    for (int c = 0; c < 3; ++c) {
      const int k = c * 64 + lane;
      float v = 0.f;
      if (k < ND)            v = erow[k];
      else if (k < ND + 3)   v = edge_identify[rid_[i] * 3 + (k - ND)];
      pg[i][c] = v;
    }
  }

  // ============ phase 0: build ef bf16[24][360] from prefetched regs + cos ============
#pragma unroll
  for (int i = 0; i < 6; ++i) {
    const int r = wv + 4 * i;
    const float dt = dt_[i];
#pragma unroll
    for (int c = 0; c < 6; ++c) {
      const int k = c * 64 + lane;   // 0..383
      float v;
      if (c < 3) {
        v = pg[i][c];
        if (k >= ND + 3) {           // c==2 lanes 47..63 -> time features
          const int d = k - (ND + 3);
          v = __cosf(fmaf(dt, basis_freq[d], phase[d]));
        }
      } else {
        v = 0.f;
        if (k < EVD) {
          const int d = k - (ND + 3);
          v = __cosf(fmaf(dt, basis_freq[d], phase[d]));
        }
      }
      if (k < 352) EF[r * EFS + k] = f2bf(v);   // 347..351 = K-pad (zero)
    }
  }

  // ============ prefetch C: node-row gathers (36 loads) — latency hides under
  // the barrier + phase-1 MFMA ============
  float ps[6][3], pt[6][3];
#pragma unroll
  for (int i = 0; i < 6; ++i) {
    const float* srow = node_embed + (long)si_[i] * ND;
    const float* trow = node_embed + (long)ti_[i] * ND;
#pragma unroll
    for (int c = 0; c < 3; ++c) {
      const int k = c * 64 + lane;
      float sv = 0.f, tv = 0.f;
      if (k < ND) { sv = srow[k]; tv = trow[k]; }
      ps[i][c] = sv;
      pt[i][c] = tv;
    }
  }
  __syncthreads();

  // ============ phase 1 (MFMA): EV[24][172] = EF[24][347] @ lin_event_w^T ============
  {
    const int nnt = (wv == 3) ? 2 : 3;   // wave w owns n-tiles {w, w+4, w+8}
    f32x4 acc[3][2];
#pragma unroll
    for (int t = 0; t < 3; ++t)
#pragma unroll
      for (int mt = 0; mt < 2; ++mt) acc[t][mt] = (f32x4){0.f, 0.f, 0.f, 0.f};

#pragma unroll 2
    for (int ks = 0; ks < 11; ++ks) {
      const int k0 = ks * 32 + q * 8;
      const bf16x8 a0 = *(const bf16x8*)&EF[mr * EFS + k0];
      const bf16x8 a1 = *(const bf16x8*)&EF[(16 + mr) * EFS + k0];
#pragma unroll 1
      for (int t = 0; t < nnt; ++t) {
        const int nt = wv + 4 * t;
        const bf16x8 b = *(const bf16x8*)&ws[W1OFF + ((nt * 11 + ks) * 64 + lane) * 8];
        acc[t][0] = __builtin_amdgcn_mfma_f32_16x16x32_bf16(a0, b, acc[t][0], 0, 0, 0);
        acc[t][1] = __builtin_amdgcn_mfma_f32_16x16x32_bf16(a1, b, acc[t][1], 0, 0, 0);
      }
    }
#pragma unroll 1
    for (int t = 0; t < nnt; ++t) {
      const int n = (wv + 4 * t) * 16 + mr;
      const float bo = (n < ND) ? lin_event_b[n] : 0.f;
#pragma unroll
      for (int mt = 0; mt < 2; ++mt)
#pragma unroll
        for (int reg = 0; reg < 4; ++reg) {
          const int m = mt * 16 + q * 4 + reg;
          if (m < 24) EV[m * EVS + n] = f2bf(acc[t][mt][reg] + bo);
        }
    }
  }
  __syncthreads();

  // ============ phase 2a: U rows from prefetched node regs + EV ============
#pragma unroll
  for (int i = 0; i < 6; ++i) {
    const int r = wv + 4 * i;
#pragma unroll
    for (int c = 0; c < 3; ++c) {
      const int k = c * 64 + lane;  // 0..191
      float u0v = 0.f, u1v = 0.f;
      if (k < ND) {
        const float e = bf2f(EV[r * EVS + k]);
        const float s = ps[i][c];
        const float t = pt[i][c];
        u0v = s + fmaxf(t + e, 0.f);
        u1v = t + fmaxf(s + e, 0.f);
      }
      U[r * US + k]        = f2bf(u0v);   // k in [172,192) zero = K-pad
      U[(32 + r) * US + k] = f2bf(u1v);
    }
  }
  __syncthreads();

  // ============ phase 2b (MFMA): H[64][64] = relu(U[64][192] @ gcn_w1^T + b1) ============
  {
    f32x4 acc[4];
#pragma unroll
    for (int nt = 0; nt < 4; ++nt) acc[nt] = (f32x4){0.f, 0.f, 0.f, 0.f};
#pragma unroll 2
    for (int ks = 0; ks < 6; ++ks) {
      const int k0 = ks * 32 + q * 8;
      const bf16x8 a = *(const bf16x8*)&U[(wv * 16 + mr) * US + k0];
#pragma unroll 1
      for (int nt = 0; nt < 4; ++nt) {
        const bf16x8 b = *(const bf16x8*)&ws[G1OFF + ((nt * 6 + ks) * 64 + lane) * 8];
        acc[nt] = __builtin_amdgcn_mfma_f32_16x16x32_bf16(a, b, acc[nt], 0, 0, 0);
      }
    }
#pragma unroll 1
    for (int nt = 0; nt < 4; ++nt) {
      const int j = nt * 16 + mr;
      const float b1 = gcn_b1[j];
#pragma unroll
      for (int reg = 0; reg < 4; ++reg) {
        const int m = wv * 16 + q * 4 + reg;
        Hs[m * HS + j] = f2bf(fmaxf(acc[nt][reg] + b1, 0.f));
      }
    }
  }
  __syncthreads();

  // ============ phase 2c (MFMA): FEATB/SRCF = H @ gcn_w2^T + b2 ============
  {
    f32x4 acc[4];
#pragma unroll
    for (int nt = 0; nt < 4; ++nt) acc[nt] = (f32x4){0.f, 0.f, 0.f, 0.f};
#pragma unroll
    for (int ks = 0; ks < 2; ++ks) {
      const int k0 = ks * 32 + q * 8;
      const bf16x8 a = *(const bf16x8*)&Hs[(wv * 16 + mr) * HS + k0];
#pragma unroll 1
      for (int nt = 0; nt < 4; ++nt) {
        const bf16x8 b = *(const bf16x8*)&ws[G2OFF + ((nt * 2 + ks) * 64 + lane) * 8];
        acc[nt] = __builtin_amdgcn_mfma_f32_16x16x32_bf16(a, b, acc[nt], 0, 0, 0);
      }
    }
#pragma unroll 1
    for (int nt = 0; nt < 4; ++nt) {
      const int j = nt * 16 + mr;
      const float b2 = gcn_b2[j];
#pragma unroll
      for (int reg = 0; reg < 4; ++reg) {
        const int m = wv * 16 + q * 4 + reg;
        int d = -1, r = 0;
        if (m < 24) { d = 0; r = m; }
        else if (m >= 32 && m < 56) { d = 1; r = m - 32; }
        if (d >= 0) {
          const float v = acc[nt][reg] + b2;
          const int n = d * HID + j;
          FEATB[r * FBS + n] = f2bf(v);
          if (r % 3 == 2) SRCF[(r / 3) * 128 + n] = v;   // src feat, fp32
        }
      }
    }
  }
  __syncthreads();

  // ============ phase 2d (MFMA): PQ = feat @ [att_w1 | att_w2]^T + bias ============
  {
    f32x4 acc[4][2];
#pragma unroll
    for (int tt = 0; tt < 4; ++tt)
#pragma unroll
      for (int mt = 0; mt < 2; ++mt) acc[tt][mt] = (f32x4){0.f, 0.f, 0.f, 0.f};
#pragma unroll 2
    for (int ks = 0; ks < 4; ++ks) {
      const int k0 = ks * 32 + q * 8;
      const bf16x8 a0 = *(const bf16x8*)&FEATB[mr * FBS + k0];
      const bf16x8 a1 = *(const bf16x8*)&FEATB[(16 + mr) * FBS + k0];
#pragma unroll 1
      for (int tt = 0; tt < 4; ++tt) {
        const int nt = wv * 4 + tt;
        const bf16x8 b = *(const bf16x8*)&ws[ATTOFF + ((nt * 4 + ks) * 64 + lane) * 8];
        acc[tt][0] = __builtin_amdgcn_mfma_f32_16x16x32_bf16(a0, b, acc[tt][0], 0, 0, 0);
        acc[tt][1] = __builtin_amdgcn_mfma_f32_16x16x32_bf16(a1, b, acc[tt][1], 0, 0, 0);
      }
    }
#pragma unroll 1
    for (int tt = 0; tt < 4; ++tt) {
      const int n = (wv * 4 + tt) * 16 + mr;   // 0..255
      const float bias = (n < D2) ? att_w1_b[n] : att_w2_b[n - D2];
#pragma unroll
      for (int mt = 0; mt < 2; ++mt)
#pragma unroll
        for (int reg = 0; reg < 4; ++reg) {
          const int m = mt * 16 + q * 4 + reg;
          if (m < 24) {
            const int l = m % 3;
            if (l == 2) { if (n < D2)  PQ[m * 128 + n]        = acc[tt][mt][reg] + bias; }
            else        { if (n >= D2) PQ[m * 128 + (n - D2)] = acc[tt][mt][reg] + bias; }
          }
        }
    }
  }
  __syncthreads();

  // ============ phase 3: softmax/out + MLP head ============
  // Wave wv owns windows ga=2wv, gb=2wv+1; both windows share one weight stream
  // (coalesced float4 loads from wsf k-tiled transposed tables).
  {
    const int ga = wv * 2, gb = ga + 1;
    float* A_a = SC + ga * 208;  float* Bb_a = A_a + 128;   // per-window scratch
    float* A_b = SC + gb * 208;  float* Bb_b = A_b + 128;

    // softmax + out (written to A slots as fp32[128])
#pragma unroll 1
    for (int it = 0; it < 2; ++it) {
      const int g = ga + it;
      float* Ao = SC + g * 208;
      const float p0  = PQ[(3 * g + 2) * 128 + lane];
      const float p1  = PQ[(3 * g + 2) * 128 + 64 + lane];
      const float q00 = PQ[(3 * g + 0) * 128 + lane];
      const float q01 = PQ[(3 * g + 0) * 128 + 64 + lane];
      const float q10 = PQ[(3 * g + 1) * 128 + lane];
      const float q11 = PQ[(3 * g + 1) * 128 + 64 + lane];
      float s0 = p0 * q00 + p1 * q01;
      float s1 = p0 * q10 + p1 * q11;
#pragma unroll
      for (int off = 32; off >= 1; off >>= 1) {
        s0 += __shfl_xor(s0, off, 64);
        s1 += __shfl_xor(s1, off, 64);
      }
      const float mx = fmaxf(s0, s1);
      const float e0 = __expf(s0 - mx), e1 = __expf(s1 - mx);
      const float inv = 1.f / (e0 + e1);
      const float a0 = e0 * inv, a1 = e1 * inv;
      Ao[lane]      = SRCF[g * 128 + lane]      + a0 * q00 + a1 * q10;
      Ao[64 + lane] = SRCF[g * 128 + 64 + lane] + a0 * q01 + a1 * q11;
    }

    const float4* M1P = wsf + M1OFF4;
    const float4* M2P = wsf + M2OFF4;
    const float4* W1P = wsf + W1OFF4;
    const float4* W2P = wsf + W2OFF4;

    // m1 = relu(att_m1 @ out + b): K=128, out n=lane; both windows fused
    {
      float aa0 = 0.f, aa1 = 0.f, bb0 = 0.f, bb1 = 0.f;
#pragma unroll 4
      for (int kb = 0; kb < 32; kb += 2) {
        const float4 w0 = M1P[kb * 64 + lane];
        const float4 w1 = M1P[(kb + 1) * 64 + lane];
        const float4 xa0 = *(const float4*)&A_a[kb * 4];
        const float4 xa1 = *(const float4*)&A_a[kb * 4 + 4];
        const float4 xb0 = *(const float4*)&A_b[kb * 4];
        const float4 xb1 = *(const float4*)&A_b[kb * 4 + 4];
        aa0 = dot4(aa0, w0, xa0); aa1 = dot4(aa1, w1, xa1);
        bb0 = dot4(bb0, w0, xb0); bb1 = dot4(bb1, w1, xb1);
      }
      const float bi = att_m1_b[lane];
      Bb_a[lane] = fmaxf(bi + aa0 + aa1, 0.f);
      Bb_b[lane] = fmaxf(bi + bb0 + bb1, 0.f);
    }

    // h = att_m2 @ m1 + b: K=64
    float hv_a, hv_b;
    {
      float aa0 = 0.f, aa1 = 0.f, bb0 = 0.f, bb1 = 0.f;
#pragma unroll 4
      for (int kb = 0; kb < 16; kb += 2) {
        const float4 w0 = M2P[kb * 64 + lane];
        const float4 w1 = M2P[(kb + 1) * 64 + lane];
        const float4 xa0 = *(const float4*)&Bb_a[kb * 4];
        const float4 xa1 = *(const float4*)&Bb_a[kb * 4 + 4];
        const float4 xb0 = *(const float4*)&Bb_b[kb * 4];
        const float4 xb1 = *(const float4*)&Bb_b[kb * 4 + 4];
        aa0 = dot4(aa0, w0, xa0); aa1 = dot4(aa1, w1, xa1);
        bb0 = dot4(bb0, w0, xb0); bb1 = dot4(bb1, w1, xb1);
      }
      const float bi = att_m2_b[lane];
      hv_a = bi + aa0 + aa1;
      hv_b = bi + bb0 + bb1;
    }

    // x = concat(h, one_hot(cat,12), 0-pad to 80) -> A slots (out is dead)
    A_a[lane] = hv_a;
    A_b[lane] = hv_b;
    if (lane < 16) {
      const int ca = cat_feat[bw0 + ga];
      const int cb = cat_feat[bw0 + gb];
      A_a[64 + lane] = (lane < 12 && ca == lane) ? 1.f : 0.f;
      A_b[64 + lane] = (lane < 12 && cb == lane) ? 1.f : 0.f;
    }

    // h1 = relu(mlp_w1 @ x + b1): 76 outs (n=lane, n2=64+(lane&15)), K=80
    {
      float an = 0.f, an2 = 0.f, bn = 0.f, bn2 = 0.f;
      const int l2 = 64 + (lane & 15);
#pragma unroll 4
      for (int kb = 0; kb < 20; ++kb) {
        const float4 wn  = W1P[kb * 80 + lane];
        const float4 wn2 = W1P[kb * 80 + l2];
        const float4 xa = *(const float4*)&A_a[kb * 4];
        const float4 xb = *(const float4*)&A_b[kb * 4];
        an  = dot4(an,  wn,  xa); an2 = dot4(an2, wn2, xa);
        bn  = dot4(bn,  wn,  xb); bn2 = dot4(bn2, wn2, xb);
      }
      const float b1n = mlp_b1[lane];
      Bb_a[lane] = fmaxf(b1n + an, 0.f);
      Bb_b[lane] = fmaxf(b1n + bn, 0.f);
      if (lane < 16) {
        const float b1n2 = (lane < 12) ? mlp_b1[64 + lane] : 0.f;
        Bb_a[64 + lane] = fmaxf(b1n2 + an2, 0.f);   // rows 76..79 -> 0
        Bb_b[64 + lane] = fmaxf(b1n2 + bn2, 0.f);
      }
    }

    // h2 = relu(mlp_w2 @ h1 + b2); z = mlp_w3 @ h2 + b3; sigmoid
    {
      float ha = 0.f, hb = 0.f;
#pragma unroll 4
      for (int kb = 0; kb < 20; ++kb) {
        const float4 w  = W2P[kb * 64 + lane];
        const float4 xa = *(const float4*)&Bb_a[kb * 4];
        const float4 xb = *(const float4*)&Bb_b[kb * 4];
        ha = dot4(ha, w, xa);
        hb = dot4(hb, w, xb);
      }
      const float b2 = mlp_b2[lane];
      const float h2a = fmaxf(b2 + ha, 0.f);
      const float h2b = fmaxf(b2 + hb, 0.f);
      const float w3 = mlp_w3[lane];
      float za = w3 * h2a, zb = w3 * h2b;
#pragma unroll
      for (int off = 32; off >= 1; off >>= 1) {
        za += __shfl_xor(za, off, 64);
        zb += __shfl_xor(zb, off, 64);
      }
      if (lane == 0) {
        const float b3 = mlp_b3[0];
        out[bw0 + ga] = 1.f / (1.f + __expf(-(za + b3)));
        out[bw0 + gb] = 1.f / (1.f + __expf(-(zb + b3)));
      }
    }
  }
}

extern "C" void kernel_launch(void* const* d_in, const int* in_sizes, int n_in,
                              void* d_out, int out_size, void* d_ws, size_t ws_size,
                              hipStream_t stream) {
  short* ws = (short*)d_ws;
  float4* wsf = (float4*)((char*)d_ws + WSF_BYTE_OFF);
  prep_weights<<<(NFRAG * 64 + 255) / 256, 256, 0, stream>>>(
      (const float*)d_in[10],  // lin_event_w
      (const float*)d_in[12],  // gcn_w1
      (const float*)d_in[14],  // gcn_w2
      (const float*)d_in[16],  // att_w1_w
      (const float*)d_in[18],  // att_w2_w
      ws);
  prep_wf<<<(NF4 + 255) / 256, 256, 0, stream>>>(
      (const float*)d_in[20],  // att_m1_w
      (const float*)d_in[22],  // att_m2_w
      (const float*)d_in[24],  // mlp_w1
      (const float*)d_in[26],  // mlp_w2
      wsf);
  tempme_fused<<<NBLK, NT, 0, stream>>>(
      (const int*)d_in[0],    // node_idx
      (const int*)d_in[1],    // edge_idx
      (const int*)d_in[2],    // cat_feat
      (const float*)d_in[3],  // t_records
      (const float*)d_in[4],  // edge_identify
      // d_in[5] cut_time_l unused by reference
      (const float*)d_in[6],  // node_embed
      (const float*)d_in[7],  // edge_embed
      (const float*)d_in[8],  // basis_freq
      (const float*)d_in[9],  // phase
      (const float*)d_in[11],  // lin_event_b
      (const float*)d_in[13],  // gcn_b1
      (const float*)d_in[15],  // gcn_b2
      (const float*)d_in[17],  // att_w1_b
      (const float*)d_in[19],  // att_w2_b
      (const float*)d_in[21],  // att_m1_b
      (const float*)d_in[23],  // att_m2_b
      (const float*)d_in[25],  // mlp_b1
      (const float*)d_in[27],  // mlp_b2
      (const float*)d_in[28],  // mlp_w3
      (const float*)d_in[29],  // mlp_b3
      ws, wsf,
      (float*)d_out);
}

// Round 5
// 479.431 us; speedup vs baseline: 1.5661x; 1.0010x over previous
//
#include <hip/hip_runtime.h>
#include <hip/hip_bf16.h>
#include <math.h>

// Problem constants
#define NW    32768   // B*W = 512*64 windows
#define G     8       // windows per block
#define NBLK  (NW / G)
#define NT    256

// Dims
#define ND    172     // NODE_DIM = EDGE_DIM = TIME_DIM
#define EVD   347     // EVENT_DIM
#define HID   64
#define D2    128
#define MLPD  76

// ---- Workspace layout ----
// [0, 222208) bytes : bf16 MFMA B-fragments
//   fragment = 64 lanes x 8 bf16; addr = (frag_id*64 + lane)*8; lane=(q<<4)|mr;
//   element j of lane: B[n = nt*16+mr][k = ks*32+q*8+j] (0 if OOB).
#define W1OFF  0
#define G1OFF  (121 * 512)
#define G2OFF  (145 * 512)
#define ATTOFF (153 * 512)
#define NFRAG  217          // bf16 region = 217*512 bf16 = 222208 B
// [222208, 317440) bytes : fp32 k-tiled transposed tables for phase-3 layers.
//   table[kb][n] = float4(w[n][4kb..4kb+3]); coalesced: lane n reads [kb][n].
#define WSF_BYTE_OFF 222208
#define M1OFF4 0            // att_m1 [32][64]  (K=128)
#define M2OFF4 2048         // att_m2 [16][64]  (K=64)
#define W1OFF4 3072         // mlp_w1 [20][80]  (K=76 pad 80, n pad 80, zeros)
#define W2OFF4 4672         // mlp_w2 [20][64]  (K=76 pad 80, zeros)
#define NF4    5952         // total float4 = 95232 B; ws total = 317440 B

// ---- LDS byte layout (32256 B -> 5 blocks/CU = 20 waves), liveness overlays ----
// Timeline of live ranges (bytes):
//  EF   bf16[32][360] @ 0      (23040)  ph0 write rows 0-23; ph1 reads rows 0-31
//                                        (24-31 garbage -> masked C rows)
//  EV   bf16[24][184] @ 23040  (8832)   ph1 out, read 2a, dead after (ends 31872)
//  U    bf16[56][200] @ 0      (22400)  2a out rows 0-23 (u0), 32-55 (u1);
//                                        2b A-reads rows 56-63 CLAMPED to 55
//  H    bf16[64][72]  @ 23040  (9216)   2b out (overlays EV-dead), read 2c (ends 32256)
//  FEATB bf16[32][136]@ 0      (8704)   2c out (U dead), read 2d
//  SRCF f32[8][128]   @ 8704   (4096)   2c out, read ph3 (ends 12800)
//  PQ   f32[24][128]  @ 12800  (12288)  2d out, read ph3 (ends 25088; U/EF dead)
//  SC   f32[8][208]   @ 0      (6656)   ph3 scratch (FEATB dead after 2d)
#define B_EF    0
#define B_EV    23040
#define B_U     0
#define B_H     23040
#define B_FEATB 0
#define B_SRCF  8704
#define B_PQ    12800
#define B_SC    0
#define LDS_BYTES 32256

#define EFS 360
#define EVS 184
#define US  200
#define HS  72
#define FBS 136

typedef __attribute__((ext_vector_type(8))) short bf16x8;
typedef __attribute__((ext_vector_type(4))) float f32x4;

// inline function, NOT a macro — macro params collide with .x/.w member tokens
static __device__ __forceinline__ float dot4(float acc, const float4 a, const float4 b) {
  acc = fmaf(a.x, b.x, acc);
  acc = fmaf(a.y, b.y, acc);
  acc = fmaf(a.z, b.z, acc);
  acc = fmaf(a.w, b.w, acc);
  return acc;
}

static __device__ __forceinline__ short f2bf(float f) {
  union { __hip_bfloat16 h; short s; } u;
  u.h = __float2bfloat16(f);
  return u.s;
}
static __device__ __forceinline__ float bf2f(short s) {
  union { float f; unsigned u; } u;
  u.u = ((unsigned)(unsigned short)s) << 16;
  return u.f;
}

// ============ prep: pack all MFMA weights as bf16 fragments into ws ============
__global__ __launch_bounds__(256) void prep_weights(
    const float* __restrict__ w1, const float* __restrict__ g1,
    const float* __restrict__ g2, const float* __restrict__ a1,
    const float* __restrict__ a2, short* __restrict__ ws)
{
  const int t = blockIdx.x * 256 + threadIdx.x;
  if (t >= NFRAG * 64) return;
  const int fid  = t >> 6;
  const int lane = t & 63;
  const int q = lane >> 4, mr = lane & 15;
  bf16x8 o;
  if (fid < 121) {
    const int nt = fid / 11, ks = fid - 11 * nt;
    const int n = nt * 16 + mr, k0 = ks * 32 + q * 8;
#pragma unroll
    for (int j = 0; j < 8; ++j) {
      const int k = k0 + j;
      o[j] = (n < ND && k < EVD) ? f2bf(w1[n * EVD + k]) : (short)0;
    }
  } else if (fid < 145) {
    const int f = fid - 121, nt = f / 6, ks = f - 6 * nt;
    const int n = nt * 16 + mr, k0 = ks * 32 + q * 8;
#pragma unroll
    for (int j = 0; j < 8; ++j) {
      const int k = k0 + j;
      o[j] = (k < ND) ? f2bf(g1[n * ND + k]) : (short)0;
    }
  } else if (fid < 153) {
    const int f = fid - 145, nt = f / 2, ks = f - 2 * nt;
    const int n = nt * 16 + mr, k0 = ks * 32 + q * 8;
#pragma unroll
    for (int j = 0; j < 8; ++j) o[j] = f2bf(g2[n * HID + k0 + j]);
  } else {
    const int f = fid - 153, nt = f / 4, ks = f - 4 * nt;
    const int n = nt * 16 + mr, k0 = ks * 32 + q * 8;
    const float* src = (n < D2) ? (a1 + n * D2) : (a2 + (n - D2) * D2);
#pragma unroll
    for (int j = 0; j < 8; ++j) o[j] = f2bf(src[k0 + j]);
  }
  *(bf16x8*)&ws[(long)t * 8] = o;
}

// ============ prep: fp32 k-tiled transposed tables for phase-3 layers ============
__global__ __launch_bounds__(256) void prep_wf(
    const float* __restrict__ m1, const float* __restrict__ m2,
    const float* __restrict__ w1, const float* __restrict__ w2,
    float4* __restrict__ wf)
{
  const int t = blockIdx.x * 256 + threadIdx.x;
  if (t >= NF4) return;
  float4 o; o.x = 0.f; o.y = 0.f; o.z = 0.f; o.w = 0.f;
  if (t < M2OFF4) {                        // att_m1: [kb<32][n<64], K=128
    const int kb = t >> 6, n = t & 63;
    const float* s = m1 + n * D2 + kb * 4;
    o.x = s[0]; o.y = s[1]; o.z = s[2]; o.w = s[3];
  } else if (t < W1OFF4) {                 // att_m2: [kb<16][n<64], K=64
    const int u = t - M2OFF4, kb = u >> 6, n = u & 63;
    const float* s = m2 + n * HID + kb * 4;
    o.x = s[0]; o.y = s[1]; o.z = s[2]; o.w = s[3];
  } else if (t < W2OFF4) {                 // mlp_w1: [kb<20][n<80], pads zeroed
    const int u = t - W1OFF4, kb = u / 80, n = u - kb * 80;
    if (n < MLPD) {
#pragma unroll
      for (int j = 0; j < 4; ++j) {
        const int k = kb * 4 + j;
        ((float*)&o)[j] = (k < MLPD) ? w1[n * MLPD + k] : 0.f;
      }
    }
  } else {                                 // mlp_w2: [kb<20][n<64], k-pad zeroed
    const int u = t - W2OFF4, kb = u >> 6, n = u & 63;
#pragma unroll
    for (int j = 0; j < 4; ++j) {
      const int k = kb * 4 + j;
      ((float*)&o)[j] = (k < MLPD) ? w2[n * MLPD + k] : 0.f;
    }
  }
  wf[t] = o;
}

__global__ __launch_bounds__(256) void tempme_fused(
    const int*   __restrict__ node_idx,      // (NW, 6)
    const int*   __restrict__ edge_idx,      // (NW, 3)
    const int*   __restrict__ cat_feat,      // (NW, 1)
    const float* __restrict__ t_records,     // (NW, 3)
    const float* __restrict__ edge_identify, // (NW, 3, 3)
    const float* __restrict__ node_embed,    // (10000, 172)
    const float* __restrict__ edge_embed,    // (200000, 172)
    const float* __restrict__ basis_freq,    // (172,)
    const float* __restrict__ phase,         // (172,)
    const float* __restrict__ lin_event_b,   // (172,)
    const float* __restrict__ gcn_b1,        // (64,)
    const float* __restrict__ gcn_b2,        // (64,)
    const float* __restrict__ att_w1_b,      // (128,)
    const float* __restrict__ att_w2_b,      // (128,)
    const float* __restrict__ att_m1_b,      // (64,)
    const float* __restrict__ att_m2_b,      // (64,)
    const float* __restrict__ mlp_b1,        // (76,)
    const float* __restrict__ mlp_b2,        // (64,)
    const float* __restrict__ mlp_w3,        // (1, 64)
    const float* __restrict__ mlp_b3,        // (1,)
    const short* __restrict__ ws,            // packed bf16 weights
    const float4* __restrict__ wsf,          // packed fp32 phase-3 tables
    float*       __restrict__ out)           // (NW,)
{
  __shared__ __align__(16) unsigned char smem[LDS_BYTES];
  short* EF    = (short*)&smem[B_EF];
  short* EV    = (short*)&smem[B_EV];
  short* U     = (short*)&smem[B_U];
  short* Hs    = (short*)&smem[B_H];
  short* FEATB = (short*)&smem[B_FEATB];
  float* SRCF  = (float*)&smem[B_SRCF];
  float* PQ    = (float*)&smem[B_PQ];
  float* SC    = (float*)&smem[B_SC];

  const int tid  = threadIdx.x;
  const int lane = tid & 63;
  const int wv   = tid >> 6;
  const int q    = lane >> 4;   // MFMA quad
  const int mr   = lane & 15;   // MFMA row/col-within-tile
  const int bw0  = blockIdx.x * G;

  // ============ prefetch A: indices (wave-uniform scalar loads) ============
  int   eidx_[6], si_[6], ti_[6], rid_[6];
  float dt_[6];
#pragma unroll
  for (int i = 0; i < 6; ++i) {
    const int r = wv + 4 * i;
    const int g = r / 3;
    const int l = r - 3 * g;
    const int bw = bw0 + g;
    const int rid = bw * 3 + l;
    rid_[i]  = rid;
    eidx_[i] = edge_idx[rid];
    si_[i]   = node_idx[bw * 6 + 2 * l];
    ti_[i]   = node_idx[bw * 6 + 2 * l + 1];
    dt_[i]   = t_records[bw * 3 + 2] - t_records[rid];
  }

  // ============ prefetch B: edge-row gathers (18 loads all in flight) ============
  float pg[6][3];
#pragma unroll
  for (int i = 0; i < 6; ++i) {
    const float* erow = edge_embed + (long)eidx_[i] * ND;
#pragma unroll
    for (int c = 0; c < 3; ++c) {
      const int k = c * 64 + lane;
      float v = 0.f;
      if (k < ND)            v = erow[k];
      else if (k < ND + 3)   v = edge_identify[rid_[i] * 3 + (k - ND)];
      pg[i][c] = v;
    }
  }

  // ============ phase 0: build ef bf16[24][360] from prefetched regs + cos ============
#pragma unroll
  for (int i = 0; i < 6; ++i) {
    const int r = wv + 4 * i;
    const float dt = dt_[i];
#pragma unroll
    for (int c = 0; c < 6; ++c) {
      const int k = c * 64 + lane;   // 0..383
      float v;
      if (c < 3) {
        v = pg[i][c];
        if (k >= ND + 3) {           // c==2 lanes 47..63 -> time features
          const int d = k - (ND + 3);
          v = __cosf(fmaf(dt, basis_freq[d], phase[d]));
        }
      } else {
        v = 0.f;
        if (k < EVD) {
          const int d = k - (ND + 3);
          v = __cosf(fmaf(dt, basis_freq[d], phase[d]));
        }
      }
      if (k < 352) EF[r * EFS + k] = f2bf(v);   // 347..351 = K-pad (zero)
    }
  }

  // ============ prefetch C: node-row gathers (36 loads) — latency hides under
  // the barrier + phase-1 MFMA ============
  float ps[6][3], pt[6][3];
#pragma unroll
  for (int i = 0; i < 6; ++i) {
    const float* srow = node_embed + (long)si_[i] * ND;
    const float* trow = node_embed + (long)ti_[i] * ND;
#pragma unroll
    for (int c = 0; c < 3; ++c) {
      const int k = c * 64 + lane;
      float sv = 0.f, tv = 0.f;
      if (k < ND) { sv = srow[k]; tv = trow[k]; }
      ps[i][c] = sv;
      pt[i][c] = tv;
    }
  }
  __syncthreads();

  // ============ phase 1 (MFMA): EV[24][172] = EF[24][347] @ lin_event_w^T ============
  {
    const int nnt = (wv == 3) ? 2 : 3;   // wave w owns n-tiles {w, w+4, w+8}
    f32x4 acc[3][2];
#pragma unroll
    for (int t = 0; t < 3; ++t)
#pragma unroll
      for (int mt = 0; mt < 2; ++mt) acc[t][mt] = (f32x4){0.f, 0.f, 0.f, 0.f};

#pragma unroll 2
    for (int ks = 0; ks < 11; ++ks) {
      const int k0 = ks * 32 + q * 8;
      const bf16x8 a0 = *(const bf16x8*)&EF[mr * EFS + k0];
      const bf16x8 a1 = *(const bf16x8*)&EF[(16 + mr) * EFS + k0];
#pragma unroll 1
      for (int t = 0; t < nnt; ++t) {
        const int nt = wv + 4 * t;
        const bf16x8 b = *(const bf16x8*)&ws[W1OFF + ((nt * 11 + ks) * 64 + lane) * 8];
        acc[t][0] = __builtin_amdgcn_mfma_f32_16x16x32_bf16(a0, b, acc[t][0], 0, 0, 0);
        acc[t][1] = __builtin_amdgcn_mfma_f32_16x16x32_bf16(a1, b, acc[t][1], 0, 0, 0);
      }
    }
#pragma unroll 1
    for (int t = 0; t < nnt; ++t) {
      const int n = (wv + 4 * t) * 16 + mr;
      const float bo = (n < ND) ? lin_event_b[n] : 0.f;
#pragma unroll
      for (int mt = 0; mt < 2; ++mt)
#pragma unroll
        for (int reg = 0; reg < 4; ++reg) {
          const int m = mt * 16 + q * 4 + reg;
          if (m < 24) EV[m * EVS + n] = f2bf(acc[t][mt][reg] + bo);
        }
    }
  }
  __syncthreads();

  // ============ phase 2a: U rows from prefetched node regs + EV ============
#pragma unroll
  for (int i = 0; i < 6; ++i) {
    const int r = wv + 4 * i;
#pragma unroll
    for (int c = 0; c < 3; ++c) {
      const int k = c * 64 + lane;  // 0..191
      float u0v = 0.f, u1v = 0.f;
      if (k < ND) {
        const float e = bf2f(EV[r * EVS + k]);
        const float s = ps[i][c];
        const float t = pt[i][c];
        u0v = s + fmaxf(t + e, 0.f);
        u1v = t + fmaxf(s + e, 0.f);
      }
      U[r * US + k]        = f2bf(u0v);   // k in [172,192) zero = K-pad
      U[(32 + r) * US + k] = f2bf(u1v);
    }
  }
  __syncthreads();

  // ============ phase 2b (MFMA): H[64][64] = relu(U[64][192] @ gcn_w1^T + b1) ============
  // A-row clamp: rows 56-63 (wv=3, mr>=8) are garbage fillers; clamp to row 55
  // so U only needs 56 rows of LDS. Their C-rows (56-63) are masked downstream.
  {
    const int urow0 = wv * 16 + mr;
    const int urow  = (urow0 > 55) ? 55 : urow0;
    f32x4 acc[4];
#pragma unroll
    for (int nt = 0; nt < 4; ++nt) acc[nt] = (f32x4){0.f, 0.f, 0.f, 0.f};
#pragma unroll 2
    for (int ks = 0; ks < 6; ++ks) {
      const int k0 = ks * 32 + q * 8;
      const bf16x8 a = *(const bf16x8*)&U[urow * US + k0];
#pragma unroll 1
      for (int nt = 0; nt < 4; ++nt) {
        const bf16x8 b = *(const bf16x8*)&ws[G1OFF + ((nt * 6 + ks) * 64 + lane) * 8];
        acc[nt] = __builtin_amdgcn_mfma_f32_16x16x32_bf16(a, b, acc[nt], 0, 0, 0);
      }
    }
#pragma unroll 1
    for (int nt = 0; nt < 4; ++nt) {
      const int j = nt * 16 + mr;
      const float b1 = gcn_b1[j];
#pragma unroll
      for (int reg = 0; reg < 4; ++reg) {
        const int m = wv * 16 + q * 4 + reg;
        Hs[m * HS + j] = f2bf(fmaxf(acc[nt][reg] + b1, 0.f));
      }
    }
  }
  __syncthreads();

  // ============ phase 2c (MFMA): FEATB/SRCF = H @ gcn_w2^T + b2 ============
  {
    f32x4 acc[4];
#pragma unroll
    for (int nt = 0; nt < 4; ++nt) acc[nt] = (f32x4){0.f, 0.f, 0.f, 0.f};
#pragma unroll
    for (int ks = 0; ks < 2; ++ks) {
      const int k0 = ks * 32 + q * 8;
      const bf16x8 a = *(const bf16x8*)&Hs[(wv * 16 + mr) * HS + k0];
#pragma unroll 1
      for (int nt = 0; nt < 4; ++nt) {
        const bf16x8 b = *(const bf16x8*)&ws[G2OFF + ((nt * 2 + ks) * 64 + lane) * 8];
        acc[nt] = __builtin_amdgcn_mfma_f32_16x16x32_bf16(a, b, acc[nt], 0, 0, 0);
      }
    }
#pragma unroll 1
    for (int nt = 0; nt < 4; ++nt) {
      const int j = nt * 16 + mr;
      const float b2 = gcn_b2[j];
#pragma unroll
      for (int reg = 0; reg < 4; ++reg) {
        const int m = wv * 16 + q * 4 + reg;
        int d = -1, r = 0;
        if (m < 24) { d = 0; r = m; }
        else if (m >= 32 && m < 56) { d = 1; r = m - 32; }
        if (d >= 0) {
          const float v = acc[nt][reg] + b2;
          const int n = d * HID + j;
          FEATB[r * FBS + n] = f2bf(v);
          if (r % 3 == 2) SRCF[(r / 3) * 128 + n] = v;   // src feat, fp32
        }
      }
    }
  }
  __syncthreads();

  // ============ phase 2d (MFMA): PQ = feat @ [att_w1 | att_w2]^T + bias ============
  {
    f32x4 acc[4][2];
#pragma unroll
    for (int tt = 0; tt < 4; ++tt)
#pragma unroll
      for (int mt = 0; mt < 2; ++mt) acc[tt][mt] = (f32x4){0.f, 0.f, 0.f, 0.f};
#pragma unroll 2
    for (int ks = 0; ks < 4; ++ks) {
      const int k0 = ks * 32 + q * 8;
      const bf16x8 a0 = *(const bf16x8*)&FEATB[mr * FBS + k0];
      const bf16x8 a1 = *(const bf16x8*)&FEATB[(16 + mr) * FBS + k0];
#pragma unroll 1
      for (int tt = 0; tt < 4; ++tt) {
        const int nt = wv * 4 + tt;
        const bf16x8 b = *(const bf16x8*)&ws[ATTOFF + ((nt * 4 + ks) * 64 + lane) * 8];
        acc[tt][0] = __builtin_amdgcn_mfma_f32_16x16x32_bf16(a0, b, acc[tt][0], 0, 0, 0);
        acc[tt][1] = __builtin_amdgcn_mfma_f32_16x16x32_bf16(a1, b, acc[tt][1], 0, 0, 0);
      }
    }
#pragma unroll 1
    for (int tt = 0; tt < 4; ++tt) {
      const int n = (wv * 4 + tt) * 16 + mr;   // 0..255
      const float bias = (n < D2) ? att_w1_b[n] : att_w2_b[n - D2];
#pragma unroll
      for (int mt = 0; mt < 2; ++mt)
#pragma unroll
        for (int reg = 0; reg < 4; ++reg) {
          const int m = mt * 16 + q * 4 + reg;
          if (m < 24) {
            const int l = m % 3;
            if (l == 2) { if (n < D2)  PQ[m * 128 + n]        = acc[tt][mt][reg] + bias; }
            else        { if (n >= D2) PQ[m * 128 + (n - D2)] = acc[tt][mt][reg] + bias; }
          }
        }
    }
  }
  __syncthreads();

  // ============ phase 3: softmax/out + MLP head ============
  // Wave wv owns windows ga=2wv, gb=2wv+1; both windows share one weight stream
  // (coalesced float4 loads from wsf k-tiled transposed tables).
  {
    const int ga = wv * 2, gb = ga + 1;
    float* A_a = SC + ga * 208;  float* Bb_a = A_a + 128;   // per-window scratch
    float* A_b = SC + gb * 208;  float* Bb_b = A_b + 128;

    // softmax + out (written to A slots as fp32[128])
#pragma unroll 1
    for (int it = 0; it < 2; ++it) {
      const int g = ga + it;
      float* Ao = SC + g * 208;
      const float p0  = PQ[(3 * g + 2) * 128 + lane];
      const float p1  = PQ[(3 * g + 2) * 128 + 64 + lane];
      const float q00 = PQ[(3 * g + 0) * 128 + lane];
      const float q01 = PQ[(3 * g + 0) * 128 + 64 + lane];
      const float q10 = PQ[(3 * g + 1) * 128 + lane];
      const float q11 = PQ[(3 * g + 1) * 128 + 64 + lane];
      float s0 = p0 * q00 + p1 * q01;
      float s1 = p0 * q10 + p1 * q11;
#pragma unroll
      for (int off = 32; off >= 1; off >>= 1) {
        s0 += __shfl_xor(s0, off, 64);
        s1 += __shfl_xor(s1, off, 64);
      }
      const float mx = fmaxf(s0, s1);
      const float e0 = __expf(s0 - mx), e1 = __expf(s1 - mx);
      const float inv = 1.f / (e0 + e1);
      const float a0 = e0 * inv, a1 = e1 * inv;
      Ao[lane]      = SRCF[g * 128 + lane]      + a0 * q00 + a1 * q10;
      Ao[64 + lane] = SRCF[g * 128 + 64 + lane] + a0 * q01 + a1 * q11;
    }

    const float4* M1P = wsf + M1OFF4;
    const float4* M2P = wsf + M2OFF4;
    const float4* W1P = wsf + W1OFF4;
    const float4* W2P = wsf + W2OFF4;

    // m1 = relu(att_m1 @ out + b): K=128, out n=lane; both windows fused
    {
      float aa0 = 0.f, aa1 = 0.f, bb0 = 0.f, bb1 = 0.f;
#pragma unroll 4
      for (int kb = 0; kb < 32; kb += 2) {
        const float4 w0 = M1P[kb * 64 + lane];
        const float4 w1 = M1P[(kb + 1) * 64 + lane];
        const float4 xa0 = *(const float4*)&A_a[kb * 4];
        const float4 xa1 = *(const float4*)&A_a[kb * 4 + 4];
        const float4 xb0 = *(const float4*)&A_b[kb * 4];
        const float4 xb1 = *(const float4*)&A_b[kb * 4 + 4];
        aa0 = dot4(aa0, w0, xa0); aa1 = dot4(aa1, w1, xa1);
        bb0 = dot4(bb0, w0, xb0); bb1 = dot4(bb1, w1, xb1);
      }
      const float bi = att_m1_b[lane];
      Bb_a[lane] = fmaxf(bi + aa0 + aa1, 0.f);
      Bb_b[lane] = fmaxf(bi + bb0 + bb1, 0.f);
    }

    // h = att_m2 @ m1 + b: K=64
    float hv_a, hv_b;
    {
      float aa0 = 0.f, aa1 = 0.f, bb0 = 0.f, bb1 = 0.f;
#pragma unroll 4
      for (int kb = 0; kb < 16; kb += 2) {
        const float4 w0 = M2P[kb * 64 + lane];
        const float4 w1 = M2P[(kb + 1) * 64 + lane];
        const float4 xa0 = *(const float4*)&Bb_a[kb * 4];
        const float4 xa1 = *(const float4*)&Bb_a[kb * 4 + 4];
        const float4 xb0 = *(const float4*)&Bb_b[kb * 4];
        const float4 xb1 = *(const float4*)&Bb_b[kb * 4 + 4];
        aa0 = dot4(aa0, w0, xa0); aa1 = dot4(aa1, w1, xa1);
        bb0 = dot4(bb0, w0, xb0); bb1 = dot4(bb1, w1, xb1);
      }
      const float bi = att_m2_b[lane];
      hv_a = bi + aa0 + aa1;
      hv_b = bi + bb0 + bb1;
    }

    // x = concat(h, one_hot(cat,12), 0-pad to 80) -> A slots (out is dead)
    A_a[lane] = hv_a;
    A_b[lane] = hv_b;
    if (lane < 16) {
      const int ca = cat_feat[bw0 + ga];
      const int cb = cat_feat[bw0 + gb];
      A_a[64 + lane] = (lane < 12 && ca == lane) ? 1.f : 0.f;
      A_b[64 + lane] = (lane < 12 && cb == lane) ? 1.f : 0.f;
    }

    // h1 = relu(mlp_w1 @ x + b1): 76 outs (n=lane, n2=64+(lane&15)), K=80
    {
      float an = 0.f, an2 = 0.f, bn = 0.f, bn2 = 0.f;
      const int l2 = 64 + (lane & 15);
#pragma unroll 4
      for (int kb = 0; kb < 20; ++kb) {
        const float4 wn  = W1P[kb * 80 + lane];
        const float4 wn2 = W1P[kb * 80 + l2];
        const float4 xa = *(const float4*)&A_a[kb * 4];
        const float4 xb = *(const float4*)&A_b[kb * 4];
        an  = dot4(an,  wn,  xa); an2 = dot4(an2, wn2, xa);
        bn  = dot4(bn,  wn,  xb); bn2 = dot4(bn2, wn2, xb);
      }
      const float b1n = mlp_b1[lane];
      Bb_a[lane] = fmaxf(b1n + an, 0.f);
      Bb_b[lane] = fmaxf(b1n + bn, 0.f);
      if (lane < 16) {
        const float b1n2 = (lane < 12) ? mlp_b1[64 + lane] : 0.f;
        Bb_a[64 + lane] = fmaxf(b1n2 + an2, 0.f);   // rows 76..79 -> 0
        Bb_b[64 + lane] = fmaxf(b1n2 + bn2, 0.f);
      }
    }

    // h2 = relu(mlp_w2 @ h1 + b2); z = mlp_w3 @ h2 + b3; sigmoid
    {
      float ha = 0.f, hb = 0.f;
#pragma unroll 4
      for (int kb = 0; kb < 20; ++kb) {
        const float4 w  = W2P[kb * 64 + lane];
        const float4 xa = *(const float4*)&Bb_a[kb * 4];
        const float4 xb = *(const float4*)&Bb_b[kb * 4];
        ha = dot4(ha, w, xa);
        hb = dot4(hb, w, xb);
      }
      const float b2 = mlp_b2[lane];
      const float h2a = fmaxf(b2 + ha, 0.f);
      const float h2b = fmaxf(b2 + hb, 0.f);
      const float w3 = mlp_w3[lane];
      float za = w3 * h2a, zb = w3 * h2b;
#pragma unroll
      for (int off = 32; off >= 1; off >>= 1) {
        za += __shfl_xor(za, off, 64);
        zb += __shfl_xor(zb, off, 64);
      }
      if (lane == 0) {
        const float b3 = mlp_b3[0];
        out[bw0 + ga] = 1.f / (1.f + __expf(-(za + b3)));
        out[bw0 + gb] = 1.f / (1.f + __expf(-(zb + b3)));
      }
    }
  }
}

extern "C" void kernel_launch(void* const* d_in, const int* in_sizes, int n_in,
                              void* d_out, int out_size, void* d_ws, size_t ws_size,
                              hipStream_t stream) {
  short* ws = (short*)d_ws;
  float4* wsf = (float4*)((char*)d_ws + WSF_BYTE_OFF);
  prep_weights<<<(NFRAG * 64 + 255) / 256, 256, 0, stream>>>(
      (const float*)d_in[10],  // lin_event_w
      (const float*)d_in[12],  // gcn_w1
      (const float*)d_in[14],  // gcn_w2
      (const float*)d_in[16],  // att_w1_w
      (const float*)d_in[18],  // att_w2_w
      ws);
  prep_wf<<<(NF4 + 255) / 256, 256, 0, stream>>>(
      (const float*)d_in[20],  // att_m1_w
      (const float*)d_in[22],  // att_m2_w
      (const float*)d_in[24],  // mlp_w1
      (const float*)d_in[26],  // mlp_w2
      wsf);
  tempme_fused<<<NBLK, NT, 0, stream>>>(
      (const int*)d_in[0],    // node_idx
      (const int*)d_in[1],    // edge_idx
      (const int*)d_in[2],    // cat_feat
      (const float*)d_in[3],  // t_records
      (const float*)d_in[4],  // edge_identify
      // d_in[5] cut_time_l unused by reference
      (const float*)d_in[6],  // node_embed
      (const float*)d_in[7],  // edge_embed
      (const float*)d_in[8],  // basis_freq
      (const float*)d_in[9],  // phase
      (const float*)d_in[11],  // lin_event_b
      (const float*)d_in[13],  // gcn_b1
      (const float*)d_in[15],  // gcn_b2
      (const float*)d_in[17],  // att_w1_b
      (const float*)d_in[19],  // att_w2_b
      (const float*)d_in[21],  // att_m1_b
      (const float*)d_in[23],  // att_m2_b
      (const float*)d_in[25],  // mlp_b1
      (const float*)d_in[27],  // mlp_b2
      (const float*)d_in[28],  // mlp_w3
      (const float*)d_in[29],  // mlp_b3
      ws, wsf,
      (float*)d_out);
}